// Round 7
// baseline (502.794 us; speedup 1.0000x reference)
//
#include <hip/hip_runtime.h>
#include <hip/hip_bf16.h>

// Problem constants (from reference)
#define NUM_USERS 100000
#define NUM_ITEMS 50000
#define N_NODES   150000   // NUM_USERS + NUM_ITEMS
#define EMB       64
#define NNZ       2400000
#define BATCH     16384
#define D_CAT     384      // EMB*3*2
#define BSHIFT    8        // 256 rows per bucket: multisplit segment ~2 lines
#define NBUCK     ((N_NODES + 255) >> 8)   // 586
#define EPB       9375     // edges per multisplit block -> grid = exactly 256

// ---- bf16 helpers (bit-level, RN-even for f32->bf16) -----------------------
__device__ __forceinline__ unsigned short f2bf(float f) {
    unsigned u = __float_as_uint(f);
    unsigned r = u + 0x7fffu + ((u >> 16) & 1u);
    return (unsigned short)(r >> 16);
}
__device__ __forceinline__ float bflo(unsigned u) { return __uint_as_float(u << 16); }
__device__ __forceinline__ float bfhi(unsigned u) { return __uint_as_float(u & 0xffff0000u); }

// ---------------------------------------------------------------------------
// Bucket histogram, LDS-aggregated (round-2 proven: 256 blocks).
// ---------------------------------------------------------------------------
__global__ __launch_bounds__(1024) void bucket_hist(const int* __restrict__ rows,
                                                    int* __restrict__ bcnt, int nnz) {
    __shared__ int h[NBUCK];
    int tid = threadIdx.x;
    for (int i = tid; i < NBUCK; i += 1024) h[i] = 0;
    __syncthreads();
    for (int i = blockIdx.x * 1024 + tid; i < nnz; i += gridDim.x * 1024)
        atomicAdd(&h[rows[i] >> BSHIFT], 1);
    __syncthreads();
    for (int i = tid; i < NBUCK; i += 1024) {
        int c = h[i];
        if (c) atomicAdd(&bcnt[i], c);
    }
}

// ---------------------------------------------------------------------------
// Exclusive scan over the 586 bucket counts (single block, 1 elem/thread).
// ---------------------------------------------------------------------------
__global__ __launch_bounds__(1024) void bucket_scan(const int* __restrict__ bcnt,
                                                    int* __restrict__ boffs,
                                                    int* __restrict__ gtails, int nnz) {
    __shared__ int s[1024];
    int t = threadIdx.x;
    int x = (t < NBUCK) ? bcnt[t] : 0;
    s[t] = x;
    __syncthreads();
#pragma unroll
    for (int off = 1; off < 1024; off <<= 1) {
        int v = (t >= off) ? s[t - off] : 0;
        __syncthreads();
        s[t] += v;
        __syncthreads();
    }
    if (t < NBUCK) {
        int e = s[t] - x;
        boffs[t] = e;
        gtails[t] = e;
    }
    if (t == 0) boffs[NBUCK] = nnz;
}

// ---------------------------------------------------------------------------
// LDS-staged multisplit into 256-row buckets (round-15 proven).
// pv payload: .x = (r_local<<18) | col  (rl<256, col<2^18), .y = val
// ---------------------------------------------------------------------------
__global__ __launch_bounds__(1024) void coarse_multisplit(const int* __restrict__ rows,
                                                          const int* __restrict__ cols,
                                                          const float* __restrict__ vals,
                                                          int* __restrict__ gtails,
                                                          int2* __restrict__ pv, int nnz) {
    extern __shared__ int dyn[];
    int2* stage = (int2*)dyn;          // [EPB]  bucket-sorted payloads (75 KB)
    int*  smap  = dyn + 2 * EPB;       // [EPB]  per-slot dst shift (37.5 KB)
    __shared__ int hcnt[NBUCK];        // counts -> then local bump cursors
    __shared__ int lstart[NBUCK];      // local exclusive prefix (immutable)
    __shared__ int shiftv[NBUCK];      // global base - local start

    int tid = threadIdx.x;
    int e0 = blockIdx.x * EPB;
    int e1 = e0 + EPB < nnz ? e0 + EPB : nnz;
    int nE = e1 - e0;

    // phase 1: local histogram
    for (int i = tid; i < NBUCK; i += 1024) hcnt[i] = 0;
    __syncthreads();
    for (int i = e0 + tid; i < e1; i += 1024)
        atomicAdd(&hcnt[rows[i] >> BSHIFT], 1);
    __syncthreads();

    // phase 2: local scan (Hillis-Steele over 1024 slots; smap[0:1024) scratch)
    int cnt = (tid < NBUCK) ? hcnt[tid] : 0;
    smap[tid] = cnt;
    __syncthreads();
#pragma unroll
    for (int off = 1; off < 1024; off <<= 1) {
        int v = (tid >= off) ? smap[tid - off] : 0;
        __syncthreads();
        smap[tid] += v;
        __syncthreads();
    }
    if (tid < NBUCK) {
        int ls = smap[tid] - cnt;      // exclusive local prefix
        lstart[tid] = ls;
        hcnt[tid] = ls;                // init bump cursor
        int gb = cnt ? atomicAdd(&gtails[tid], cnt) : 0;  // global base
        shiftv[tid] = gb - ls;
    }
    __syncthreads();

    // phase 3: fill per-slot shift map (avg 14, bounded run per bucket)
    for (int b = tid; b < NBUCK; b += 1024) {
        int beg = lstart[b];
        int end_ = (b == NBUCK - 1) ? nE : lstart[b + 1];
        int sh = shiftv[b];
        for (int k = beg; k < end_; ++k) smap[k] = sh;
    }
    __syncthreads();

    // phase 4: placement into bucket-sorted LDS slots (rows re-read: L2-warm)
    for (int i = e0 + tid; i < e1; i += 1024) {
        int r = rows[i];
        int p = atomicAdd(&hcnt[r >> BSHIFT], 1);
        stage[p] = make_int2(((r & 255) << 18) | cols[i], __float_as_int(vals[i]));
    }
    __syncthreads();

    // phase 5: coalesced flush (consecutive lanes -> consecutive dst per run)
    for (int j = tid; j < nE; j += 1024)
        pv[smap[j] + j] = stage[j];
}

// ---------------------------------------------------------------------------
// Fine scatter within a 256-row bucket + row_ptr production.
// ---------------------------------------------------------------------------
__global__ __launch_bounds__(1024) void fine_scatter(const int* __restrict__ boffs,
                                                     const int2* __restrict__ pv,
                                                     int2* __restrict__ packed,
                                                     int* __restrict__ row_ptr, int nnz) {
    __shared__ int rcnt[256];
    __shared__ int loff[256];
    int b = blockIdx.x;
    int tid = threadIdx.x;
    int lo = boffs[b], hi = boffs[b + 1];
    int r0 = b << BSHIFT;
    int nr = N_NODES - r0; if (nr > 256) nr = 256;

    if (tid < 256) rcnt[tid] = 0;
    __syncthreads();
    for (int i = lo + tid; i < hi; i += 1024)
        atomicAdd(&rcnt[pv[i].x >> 18], 1);
    __syncthreads();
    if (tid < 256) loff[tid] = rcnt[tid];
    __syncthreads();
#pragma unroll
    for (int off = 1; off < 256; off <<= 1) {
        int v = (tid < 256 && tid >= off) ? loff[tid - off] : 0;
        __syncthreads();
        if (tid < 256) loff[tid] += v;
        __syncthreads();
    }
    if (tid < 256) {
        int e = lo + loff[tid] - rcnt[tid];    // exclusive prefix + bucket base
        loff[tid] = e;
        if (tid < nr) row_ptr[r0 + tid] = e;
    }
    if (b == 0 && tid == 0) row_ptr[N_NODES] = nnz;
    __syncthreads();
    for (int i = lo + tid; i < hi; i += 1024) {
        int2 e = pv[i];
        int rl = e.x >> 18;
        int pos = atomicAdd(&loff[rl], 1);
        packed[pos] = make_int2(e.x & 0x3FFFF, e.y);
    }
}

// ---------------------------------------------------------------------------
// Layer-1 table GEMM (round-2 proven LDS version; round-19/20 SGPR variant
// regressed +25 us: streamed s_loads miss the small scalar L1 -> serialized
// ~250 cy L2 round-trips. Reverted).
// ---------------------------------------------------------------------------
__global__ __launch_bounds__(256) void gemm_table_f32(const float* __restrict__ uE,
                                                      const float* __restrict__ iE,
                                                      const float* __restrict__ W,
                                                      unsigned short* __restrict__ Zh,
                                                      int n_rows) {
    __shared__ float Wl[64 * 64];        // 16 KB
    __shared__ float Xf[64 * 64];        // 16 KB
    int tid = threadIdx.x;
    int lane = tid & 63;
    int wave = tid >> 6;
    int r0 = blockIdx.x * 64;
    int last = n_rows - 1;

    for (int i = tid; i < 64 * 64; i += 256) Wl[i] = W[i];
    for (int i = tid; i < 64 * 16; i += 256) {       // 1024 float4
        int row = i >> 4, q = i & 15;
        int r = r0 + row; r = r > last ? last : r;
        const float4* src = (r < NUM_USERS)
            ? (const float4*)(uE + (size_t)r * 64)
            : (const float4*)(iE + (size_t)(r - NUM_USERS) * 64);
        ((float4*)Xf)[i] = src[q];
    }
    __syncthreads();

    int rbase = wave * 16;
    float acc[16];
#pragma unroll
    for (int i = 0; i < 16; ++i) acc[i] = 0.f;

#pragma unroll 1
    for (int kc = 0; kc < 16; ++kc) {    // 4 k-values per chunk
        float w0 = Wl[(kc * 4 + 0) * 64 + lane];
        float w1 = Wl[(kc * 4 + 1) * 64 + lane];
        float w2 = Wl[(kc * 4 + 2) * 64 + lane];
        float w3 = Wl[(kc * 4 + 3) * 64 + lane];
#pragma unroll
        for (int i = 0; i < 16; ++i) {
            float4 q = ((const float4*)Xf)[(rbase + i) * 16 + kc];  // LDS broadcast
            acc[i] = fmaf(q.x, w0, acc[i]);
            acc[i] = fmaf(q.y, w1, acc[i]);
            acc[i] = fmaf(q.z, w2, acc[i]);
            acc[i] = fmaf(q.w, w3, acc[i]);
        }
    }
#pragma unroll
    for (int i = 0; i < 16; ++i) {
        int r = r0 + rbase + i;
        if (r < n_rows) Zh[(size_t)r * 64 + lane] = f2bf(acc[i]);
    }
}

// ---------------------------------------------------------------------------
// Layer-2 table GEMM (round-2 proven LDS version; FALLBACK only — used when
// the workspace can't hold the fused Zh2 buffer).
// ---------------------------------------------------------------------------
__global__ __launch_bounds__(256) void gemm_table_bf16(const unsigned* __restrict__ Xh,
                                                       const float* __restrict__ W,
                                                       unsigned short* __restrict__ Zh,
                                                       int n_rows) {
    __shared__ float Wl[64 * 64];        // 16 KB
    __shared__ uint4 Xl4[64 * 8];        // 8 KB: 64 rows x 32 uints (bf16x2)
    int tid = threadIdx.x;
    int lane = tid & 63;
    int wave = tid >> 6;
    int r0 = blockIdx.x * 64;
    int nr = n_rows - r0; if (nr > 64) nr = 64;

    for (int i = tid; i < 64 * 64; i += 256) Wl[i] = W[i];
    const uint4* Xg4 = (const uint4*)(Xh + (size_t)r0 * 32);
    for (int i = tid; i < nr * 8; i += 256) Xl4[i] = Xg4[i];
    __syncthreads();

    const unsigned* Xl = (const unsigned*)Xl4;
    int rbase = wave * 16;
    float acc[16];
#pragma unroll
    for (int i = 0; i < 16; ++i) acc[i] = 0.f;

#pragma unroll 1
    for (int kc = 0; kc < 8; ++kc) {     // 8 k-values per chunk
        float w0 = Wl[(kc * 8 + 0) * 64 + lane];
        float w1 = Wl[(kc * 8 + 1) * 64 + lane];
        float w2 = Wl[(kc * 8 + 2) * 64 + lane];
        float w3 = Wl[(kc * 8 + 3) * 64 + lane];
        float w4 = Wl[(kc * 8 + 4) * 64 + lane];
        float w5 = Wl[(kc * 8 + 5) * 64 + lane];
        float w6 = Wl[(kc * 8 + 6) * 64 + lane];
        float w7 = Wl[(kc * 8 + 7) * 64 + lane];
#pragma unroll
        for (int i = 0; i < 16; ++i) {
            uint4 q = *(const uint4*)&Xl[(rbase + i) * 32 + kc * 4];  // broadcast
            acc[i] = fmaf(bflo(q.x), w0, acc[i]);
            acc[i] = fmaf(bfhi(q.x), w1, acc[i]);
            acc[i] = fmaf(bflo(q.y), w2, acc[i]);
            acc[i] = fmaf(bfhi(q.y), w3, acc[i]);
            acc[i] = fmaf(bflo(q.z), w4, acc[i]);
            acc[i] = fmaf(bfhi(q.z), w5, acc[i]);
            acc[i] = fmaf(bflo(q.w), w6, acc[i]);
            acc[i] = fmaf(bfhi(q.w), w7, acc[i]);
        }
    }
#pragma unroll
    for (int i = 0; i < 16; ++i) {
        int r = r0 + rbase + i;
        if (r < n_rows) Zh[(size_t)r * 64 + lane] = f2bf(acc[i]);
    }
}

// ---------------------------------------------------------------------------
// SPMM + bias + relu (round-2 proven, 1 row/wave) — used for layer 2.
// ---------------------------------------------------------------------------
__global__ __launch_bounds__(256) void spmm_bias_relu(const int* __restrict__ row_ptr,
                                                      const int2* __restrict__ packed,
                                                      const uint2* __restrict__ zh2,   // bf16x4, 16/row
                                                      const float* __restrict__ bias,  // [64] fp32
                                                      uint2* __restrict__ outh2,       // bf16x4, 16/row
                                                      int n_rows) {
    int tid = threadIdx.x;
    int lane = tid & 63;
    int wave = tid >> 6;
    int q = lane >> 4;                 // 0..3 quarter
    int k = lane & 15;                 // column group (4 cols per lane)
    int r = blockIdx.x * 4 + wave;
    if (r >= n_rows) return;

    uint2 su = zh2[(size_t)r * 16 + k];
    float4 acc;
    acc.x = q ? 0.f : bflo(su.x);
    acc.y = q ? 0.f : bfhi(su.x);
    acc.z = q ? 0.f : bflo(su.y);
    acc.w = q ? 0.f : bfhi(su.y);

    int e = row_ptr[r] + q;
    int end = row_ptr[r + 1];
    for (; e + 13 < end; e += 16) {    // 16 edges/iter (4 per quarter)
        int2 p0 = packed[e + 0];
        int2 p1 = packed[e + 4];
        int2 p2 = packed[e + 8];
        int2 p3 = packed[e + 12];
        uint2 z0 = zh2[(size_t)p0.x * 16 + k];
        uint2 z1 = zh2[(size_t)p1.x * 16 + k];
        uint2 z2 = zh2[(size_t)p2.x * 16 + k];
        uint2 z3 = zh2[(size_t)p3.x * 16 + k];
        float v0 = __int_as_float(p0.y), v1 = __int_as_float(p1.y);
        float v2 = __int_as_float(p2.y), v3 = __int_as_float(p3.y);
        acc.x = fmaf(v0, bflo(z0.x), acc.x); acc.y = fmaf(v0, bfhi(z0.x), acc.y);
        acc.z = fmaf(v0, bflo(z0.y), acc.z); acc.w = fmaf(v0, bfhi(z0.y), acc.w);
        acc.x = fmaf(v1, bflo(z1.x), acc.x); acc.y = fmaf(v1, bfhi(z1.x), acc.y);
        acc.z = fmaf(v1, bflo(z1.y), acc.z); acc.w = fmaf(v1, bfhi(z1.y), acc.w);
        acc.x = fmaf(v2, bflo(z2.x), acc.x); acc.y = fmaf(v2, bfhi(z2.x), acc.y);
        acc.z = fmaf(v2, bflo(z2.y), acc.z); acc.w = fmaf(v2, bfhi(z2.y), acc.w);
        acc.x = fmaf(v3, bflo(z3.x), acc.x); acc.y = fmaf(v3, bfhi(z3.x), acc.y);
        acc.z = fmaf(v3, bflo(z3.y), acc.z); acc.w = fmaf(v3, bfhi(z3.y), acc.w);
    }
    for (; e < end; e += 4) {
        int2 p = packed[e];
        uint2 z = zh2[(size_t)p.x * 16 + k];
        float v = __int_as_float(p.y);
        acc.x = fmaf(v, bflo(z.x), acc.x); acc.y = fmaf(v, bfhi(z.x), acc.y);
        acc.z = fmaf(v, bflo(z.y), acc.z); acc.w = fmaf(v, bfhi(z.y), acc.w);
    }

    acc.x += __shfl_xor(acc.x, 16, 64);
    acc.y += __shfl_xor(acc.y, 16, 64);
    acc.z += __shfl_xor(acc.z, 16, 64);
    acc.w += __shfl_xor(acc.w, 16, 64);
    acc.x += __shfl_xor(acc.x, 32, 64);
    acc.y += __shfl_xor(acc.y, 32, 64);
    acc.z += __shfl_xor(acc.z, 32, 64);
    acc.w += __shfl_xor(acc.w, 32, 64);
    if (q == 0) {
        float4 bv = ((const float4*)bias)[k];
        float a = fmaxf(acc.x + bv.x, 0.f);
        float b = fmaxf(acc.y + bv.y, 0.f);
        float c = fmaxf(acc.z + bv.z, 0.f);
        float d = fmaxf(acc.w + bv.w, 0.f);
        outh2[(size_t)r * 16 + k] = make_uint2(
            ((unsigned)f2bf(b) << 16) | (unsigned)f2bf(a),
            ((unsigned)f2bf(d) << 16) | (unsigned)f2bf(c));
    }
}

// ---------------------------------------------------------------------------
// Layer-1 SPMM + bias + relu + fused Z2 = bf16(row)@Wz (round-21).
// Round-4's fused epilogue was DS-bound (+84 us: LDS-broadcast W + shfl);
// this version is ZERO-DS: after the butterfly every lane holds the full
// reduced row in (pa,pb); readlane(imm) broadcasts row elems to SGPRs and
// the FMA hits a W-column held in 64 VGPRs (loaded once per wave, L2-hot).
// 16 rows/wave amortize the W load (L2 traffic 150 MB total).
// k ascending j=0..63 -> bit-identical to the deleted gemm_table_bf16.
// ---------------------------------------------------------------------------
__global__ __launch_bounds__(256) void spmm_bias_relu_z(const int* __restrict__ row_ptr,
                                                        const int2* __restrict__ packed,
                                                        const uint2* __restrict__ zh2,
                                                        const float* __restrict__ bias,
                                                        uint2* __restrict__ outh2,
                                                        const float* __restrict__ Wz,
                                                        unsigned short* __restrict__ Zh_out,
                                                        int n_rows) {
    int tid = threadIdx.x;
    int lane = tid & 63;
    int wave = tid >> 6;
    int q = lane >> 4;                 // 0..3 quarter
    int k = lane & 15;                 // column group (4 cols per lane)

    // W column in VGPRs, once per wave (coalesced, L2-hot: 16 KB shared)
    float wreg[64];
#pragma unroll
    for (int j = 0; j < 64; ++j) wreg[j] = Wz[j * 64 + lane];

    float4 bv = ((const float4*)bias)[k];
    int rbase = (blockIdx.x * 4 + wave) * 16;

#pragma unroll 1
    for (int ii = 0; ii < 16; ++ii) {
        int r = rbase + ii;
        if (r >= n_rows) break;        // wave-uniform

        uint2 su = zh2[(size_t)r * 16 + k];
        float4 acc;
        acc.x = q ? 0.f : bflo(su.x);
        acc.y = q ? 0.f : bfhi(su.x);
        acc.z = q ? 0.f : bflo(su.y);
        acc.w = q ? 0.f : bfhi(su.y);

        int e = row_ptr[r] + q;
        int end = row_ptr[r + 1];
        for (; e + 13 < end; e += 16) {    // 16 edges/iter (4 per quarter)
            int2 p0 = packed[e + 0];
            int2 p1 = packed[e + 4];
            int2 p2 = packed[e + 8];
            int2 p3 = packed[e + 12];
            uint2 z0 = zh2[(size_t)p0.x * 16 + k];
            uint2 z1 = zh2[(size_t)p1.x * 16 + k];
            uint2 z2 = zh2[(size_t)p2.x * 16 + k];
            uint2 z3 = zh2[(size_t)p3.x * 16 + k];
            float v0 = __int_as_float(p0.y), v1 = __int_as_float(p1.y);
            float v2 = __int_as_float(p2.y), v3 = __int_as_float(p3.y);
            acc.x = fmaf(v0, bflo(z0.x), acc.x); acc.y = fmaf(v0, bfhi(z0.x), acc.y);
            acc.z = fmaf(v0, bflo(z0.y), acc.z); acc.w = fmaf(v0, bfhi(z0.y), acc.w);
            acc.x = fmaf(v1, bflo(z1.x), acc.x); acc.y = fmaf(v1, bfhi(z1.x), acc.y);
            acc.z = fmaf(v1, bflo(z1.y), acc.z); acc.w = fmaf(v1, bfhi(z1.y), acc.w);
            acc.x = fmaf(v2, bflo(z2.x), acc.x); acc.y = fmaf(v2, bfhi(z2.x), acc.y);
            acc.z = fmaf(v2, bflo(z2.y), acc.z); acc.w = fmaf(v2, bfhi(z2.y), acc.w);
            acc.x = fmaf(v3, bflo(z3.x), acc.x); acc.y = fmaf(v3, bfhi(z3.x), acc.y);
            acc.z = fmaf(v3, bflo(z3.y), acc.z); acc.w = fmaf(v3, bfhi(z3.y), acc.w);
        }
        for (; e < end; e += 4) {
            int2 p = packed[e];
            uint2 z = zh2[(size_t)p.x * 16 + k];
            float v = __int_as_float(p.y);
            acc.x = fmaf(v, bflo(z.x), acc.x); acc.y = fmaf(v, bfhi(z.x), acc.y);
            acc.z = fmaf(v, bflo(z.y), acc.z); acc.w = fmaf(v, bfhi(z.y), acc.w);
        }

        acc.x += __shfl_xor(acc.x, 16, 64);
        acc.y += __shfl_xor(acc.y, 16, 64);
        acc.z += __shfl_xor(acc.z, 16, 64);
        acc.w += __shfl_xor(acc.w, 16, 64);
        acc.x += __shfl_xor(acc.x, 32, 64);
        acc.y += __shfl_xor(acc.y, 32, 64);
        acc.z += __shfl_xor(acc.z, 32, 64);
        acc.w += __shfl_xor(acc.w, 32, 64);

        // bias+relu+round on ALL lanes (quarters hold identical sums)
        float a = fmaxf(acc.x + bv.x, 0.f);
        float b = fmaxf(acc.y + bv.y, 0.f);
        float c = fmaxf(acc.z + bv.z, 0.f);
        float d = fmaxf(acc.w + bv.w, 0.f);
        int pa = (int)(((unsigned)f2bf(b) << 16) | (unsigned)f2bf(a));
        int pb = (int)(((unsigned)f2bf(d) << 16) | (unsigned)f2bf(c));
        if (q == 0)
            outh2[(size_t)r * 16 + k] = make_uint2((unsigned)pa, (unsigned)pb);

        // Z2[r][lane] = sum_j row[j]*Wz[j][lane], j ascending — zero DS:
        // readlane(imm) -> SGPR broadcast, FMA against VGPR-resident W col.
        float z = 0.f;
#pragma unroll
        for (int jj = 0; jj < 16; ++jj) {
            unsigned ua = (unsigned)__builtin_amdgcn_readlane(pa, jj);
            unsigned ub = (unsigned)__builtin_amdgcn_readlane(pb, jj);
            z = fmaf(bflo(ua), wreg[4 * jj + 0], z);
            z = fmaf(bfhi(ua), wreg[4 * jj + 1], z);
            z = fmaf(bflo(ub), wreg[4 * jj + 2], z);
            z = fmaf(bfhi(ub), wreg[4 * jj + 3], z);
        }
        Zh_out[(size_t)r * 64 + lane] = f2bf(z);
    }
}

// ---------------------------------------------------------------------------
// Fused MLP (round-16 proven: 1024 threads/block, 16 waves/CU, 4 rows/wave).
// ---------------------------------------------------------------------------
__global__ __launch_bounds__(1024) void fused_mlp(
        const int* __restrict__ userIdx, const int* __restrict__ itemIdx,
        const float* __restrict__ uEmb, const float* __restrict__ iEmb,
        const unsigned short* __restrict__ feat1h,
        const unsigned short* __restrict__ feat2h,
        const float* __restrict__ W1, const float* __restrict__ b1,
        const float* __restrict__ W2, const float* __restrict__ b2,
        const float* __restrict__ W3, const float* __restrict__ b3,
        float* __restrict__ out) {
    __shared__ float    Wl[128 * 64];   // 32 KB  W1 chunk
    __shared__ unsigned El[64 * 64];    // 16 KB  E tile (bf16x2)
    __shared__ float    Ht[64 * 64];    // 16 KB  relu(E@W1+b1) tile
    __shared__ float    W2l[64 * 32];   // 8 KB
    __shared__ float    w3l[32];
    __shared__ float    b2l[32];
    __shared__ int      uidx[64], iidx[64];
    int tid = threadIdx.x;
    int lane = tid & 63;
    int wave = tid >> 6;                // 0..15
    int r0 = blockIdx.x * 64;
    int rbase = wave * 4;               // 4 rows per wave

    if (tid < 64) uidx[tid] = userIdx[r0 + tid];
    else if (tid < 128) iidx[tid - 64] = itemIdx[r0 + tid - 64];
    if (tid < 32) { w3l[tid] = W3[tid]; b2l[tid] = b2[tid]; }
    for (int i = tid; i < 64 * 32; i += 1024) W2l[i] = W2[i];

    float acc[4];
    float bv = b1[lane];
#pragma unroll
    for (int i = 0; i < 4; ++i) acc[i] = bv;

#pragma unroll 1
    for (int c = 0; c < 3; ++c) {
        __syncthreads();   // idx ready (c=0); El/Wl reuse safe (c>0)
        for (int i = tid; i < 128 * 64; i += 1024) Wl[i] = W1[c * 128 * 64 + i];
        {   // E-tile build: 1024 work items == 1024 threads (one gather each)
            int t = tid;                          // 64 rows x 2 segs x 8 quads
            int row = t >> 4;
            int seg = (t >> 3) & 1;
            int q   = t & 7;
            int gseg = c * 2 + seg;               // 0..5
            uint4 val;
            if (gseg == 0 || gseg == 3) {         // fp32 embedding segment
                const float* p = (gseg == 0)
                    ? uEmb + (size_t)uidx[row] * 64 + q * 8
                    : iEmb + (size_t)iidx[row] * 64 + q * 8;
                float4 a = *(const float4*)p;
                float4 b = *(const float4*)(p + 4);
                val.x = ((unsigned)f2bf(a.y) << 16) | f2bf(a.x);
                val.y = ((unsigned)f2bf(a.w) << 16) | f2bf(a.z);
                val.z = ((unsigned)f2bf(b.y) << 16) | f2bf(b.x);
                val.w = ((unsigned)f2bf(b.w) << 16) | f2bf(b.z);
            } else {
                const unsigned short* src;
                if (gseg == 1)      src = feat1h + (size_t)uidx[row] * 64;
                else if (gseg == 2) src = feat2h + (size_t)uidx[row] * 64;
                else if (gseg == 4) src = feat1h + (size_t)(iidx[row] + NUM_USERS) * 64;
                else                src = feat2h + (size_t)(iidx[row] + NUM_USERS) * 64;
                val = *(const uint4*)(src + q * 8);
            }
            *(uint4*)&El[row * 64 + seg * 32 + q * 4] = val;
        }
        __syncthreads();
        const uint4* El4 = (const uint4*)El;
#pragma unroll 1
        for (int k = 0; k < 128; k += 8) {
            float w0 = Wl[(k + 0) * 64 + lane];
            float w1 = Wl[(k + 1) * 64 + lane];
            float w2 = Wl[(k + 2) * 64 + lane];
            float w3 = Wl[(k + 3) * 64 + lane];
            float w4 = Wl[(k + 4) * 64 + lane];
            float w5 = Wl[(k + 5) * 64 + lane];
            float w6 = Wl[(k + 6) * 64 + lane];
            float w7 = Wl[(k + 7) * 64 + lane];
#pragma unroll
            for (int i = 0; i < 4; ++i) {
                uint4 q = El4[(rbase + i) * 16 + (k >> 3)];   // LDS broadcast
                acc[i] = fmaf(bflo(q.x), w0, acc[i]);
                acc[i] = fmaf(bfhi(q.x), w1, acc[i]);
                acc[i] = fmaf(bflo(q.y), w2, acc[i]);
                acc[i] = fmaf(bfhi(q.y), w3, acc[i]);
                acc[i] = fmaf(bflo(q.z), w4, acc[i]);
                acc[i] = fmaf(bfhi(q.z), w5, acc[i]);
                acc[i] = fmaf(bflo(q.w), w6, acc[i]);
                acc[i] = fmaf(bfhi(q.w), w7, acc[i]);
            }
        }
    }

    // H-tile: relu
#pragma unroll
    for (int i = 0; i < 4; ++i) Ht[(rbase + i) * 64 + lane] = fmaxf(acc[i], 0.f);
    __syncthreads();

    // W2/W3 finish: half-wave per row (lanes k<32 = W2 cols), shfl reduce
    int half = lane >> 5;
    int k = lane & 31;
    float b3v = b3[0];
#pragma unroll 1
    for (int p = 0; p < 2; ++p) {
        int row = rbase + p * 2 + half;
        float z = b2l[k];
#pragma unroll
        for (int j = 0; j < 64; ++j)
            z = fmaf(Ht[row * 64 + j], W2l[j * 32 + k], z);
        z *= w3l[k];
#pragma unroll
        for (int off = 16; off; off >>= 1)
            z += __shfl_xor(z, off, 64);
        if (k == 0) out[r0 + row] = z + b3v;
    }
}

// ---------------------------------------------------------------------------
extern "C" void kernel_launch(void* const* d_in, const int* in_sizes, int n_in,
                              void* d_out, int out_size, void* d_ws, size_t ws_size,
                              hipStream_t stream) {
    const int*   userIdx = (const int*)  d_in[0];
    const int*   itemIdx = (const int*)  d_in[1];
    const int*   lap_rows= (const int*)  d_in[2];
    const int*   lap_cols= (const int*)  d_in[3];
    const float* lap_vals= (const float*)d_in[4];
    const float* uEmb    = (const float*)d_in[5];
    const float* iEmb    = (const float*)d_in[6];
    const float* gW0     = (const float*)d_in[7];
    const float* gb0     = (const float*)d_in[8];
    const float* gW1     = (const float*)d_in[9];
    const float* gb1     = (const float*)d_in[10];
    const float* W1      = (const float*)d_in[11];
    const float* b1      = (const float*)d_in[12];
    const float* W2      = (const float*)d_in[13];
    const float* b2      = (const float*)d_in[14];
    const float* W3      = (const float*)d_in[15];
    const float* b3      = (const float*)d_in[16];
    float* out = (float*)d_out;

    const size_t NF = (size_t)N_NODES * EMB;              // 9.6M elements
    char* w = (char*)d_ws;
    unsigned short* bufA = (unsigned short*)w;            // feat1h (19.2 MB)
    unsigned short* bufB = bufA + NF;                     // feat2h (19.2 MB)
    char*  region3 = (char*)(bufB + NF);                  // 38.4 MB multi-use
    // region3 first half: pv during CSR build, then Zh (layer-1 Z)
    int2*  pv      = (int2*)region3;                      // 19.2 MB (dead after fine_scatter)
    unsigned short* Zh = (unsigned short*)region3;        // Z1 table (19.2 MB)
    // region3 second half: packed lives through both spmm calls
    int2*  packed  = (int2*)(region3 + NF * sizeof(float)); // 19.2 MB
    int*   row_ptr = (int*)(packed + NNZ);                // N_NODES+1
    int*   boffs   = row_ptr + (N_NODES + 1);             // NBUCK+1 (immutable)
    int*   gtails  = boffs + (NBUCK + 1);                 // NBUCK (mutable tails)
    int*   bcnt    = gtails + NBUCK;                      // NBUCK
    // Z2 table at workspace tail (spmm1 reads Z1 while writing Z2 -> distinct)
    size_t tail_off = ((size_t)((char*)(bcnt + NBUCK) - w) + 15) & ~(size_t)15;
    unsigned short* Zh2 = (unsigned short*)(w + tail_off);
    bool fuse = (tail_off + NF * sizeof(unsigned short)) <= ws_size;

    const int ms_grid   = (NNZ + EPB - 1) / EPB;          // 256 (1 block/CU)
    const int ms_lds    = EPB * 12;                       // stage (8B) + smap (4B)
    const int spmm_grid = (N_NODES + 3) / 4;              // 37500 (1 row/wave)
    const int spmmz_grid= (N_NODES + 63) / 64;            // 2344 (16 rows/wave)
    const int gemm_grid = (N_NODES + 63) / 64;            // 2344

    // ---- Build bucketed CSR (shared by both layers) — round-2 pipeline
    hipMemsetAsync(bcnt, 0, NBUCK * sizeof(int), stream);
    bucket_hist<<<256, 1024, 0, stream>>>(lap_rows, bcnt, NNZ);
    bucket_scan<<<1, 1024, 0, stream>>>(bcnt, boffs, gtails, NNZ);
    coarse_multisplit<<<ms_grid, 1024, ms_lds, stream>>>(lap_rows, lap_cols, lap_vals,
                                                         gtails, pv, NNZ);
    fine_scatter<<<NBUCK, 1024, 0, stream>>>(boffs, pv, packed, row_ptr, NNZ);

    // ---- Layer 1: Z1 = concat(uEmb,iEmb)@gW0 ; feat1 = relu((L+I)Z1 + gb0)
    gemm_table_f32<<<gemm_grid, 256, 0, stream>>>(uEmb, iEmb, gW0, Zh, N_NODES);

    if (fuse) {
        // spmm1 + fused Z2 (zero-DS readlane epilogue) — deletes gemm_table_bf16
        spmm_bias_relu_z<<<spmmz_grid, 256, 0, stream>>>(row_ptr, packed,
            (const uint2*)Zh, gb0, (uint2*)bufA, gW1, Zh2, N_NODES);
        spmm_bias_relu<<<spmm_grid, 256, 0, stream>>>(row_ptr, packed,
            (const uint2*)Zh2, gb1, (uint2*)bufB, N_NODES);
    } else {
        // fallback: original 3-kernel middle section
        spmm_bias_relu<<<spmm_grid, 256, 0, stream>>>(row_ptr, packed,
            (const uint2*)Zh, gb0, (uint2*)bufA, N_NODES);
        gemm_table_bf16<<<gemm_grid, 256, 0, stream>>>((const unsigned*)bufA, gW1,
                                                       Zh, N_NODES);
        spmm_bias_relu<<<spmm_grid, 256, 0, stream>>>(row_ptr, packed,
            (const uint2*)Zh, gb1, (uint2*)bufB, N_NODES);
    }

    // ---- Fused MLP: gather + E@W1+b1+relu + @W2+b2 + @W3+b3
    fused_mlp<<<BATCH / 64, 1024, 0, stream>>>(userIdx, itemIdx, uEmb, iEmb,
                                               bufA, bufB, W1, b1, W2, b2, W3, b3, out);
}

// Round 8
// 493.618 us; speedup vs baseline: 1.0186x; 1.0186x over previous
//
#include <hip/hip_runtime.h>
#include <hip/hip_bf16.h>

// Problem constants (from reference)
#define NUM_USERS 100000
#define NUM_ITEMS 50000
#define N_NODES   150000   // NUM_USERS + NUM_ITEMS
#define EMB       64
#define NNZ       2400000
#define BATCH     16384
#define D_CAT     384      // EMB*3*2
#define BSHIFT    8        // 256 rows per bucket: multisplit segment ~2 lines
#define NBUCK     ((N_NODES + 255) >> 8)   // 586
#define EPB       9375     // edges per multisplit block -> grid = exactly 256

// ---- bf16 helpers (bit-level, RN-even for f32->bf16) -----------------------
__device__ __forceinline__ unsigned short f2bf(float f) {
    unsigned u = __float_as_uint(f);
    unsigned r = u + 0x7fffu + ((u >> 16) & 1u);
    return (unsigned short)(r >> 16);
}
__device__ __forceinline__ float bflo(unsigned u) { return __uint_as_float(u << 16); }
__device__ __forceinline__ float bfhi(unsigned u) { return __uint_as_float(u & 0xffff0000u); }

// ---------------------------------------------------------------------------
// Bucket histogram, LDS-aggregated (round-2 proven: 256 blocks).
// ---------------------------------------------------------------------------
__global__ __launch_bounds__(1024) void bucket_hist(const int* __restrict__ rows,
                                                    int* __restrict__ bcnt, int nnz) {
    __shared__ int h[NBUCK];
    int tid = threadIdx.x;
    for (int i = tid; i < NBUCK; i += 1024) h[i] = 0;
    __syncthreads();
    for (int i = blockIdx.x * 1024 + tid; i < nnz; i += gridDim.x * 1024)
        atomicAdd(&h[rows[i] >> BSHIFT], 1);
    __syncthreads();
    for (int i = tid; i < NBUCK; i += 1024) {
        int c = h[i];
        if (c) atomicAdd(&bcnt[i], c);
    }
}

// ---------------------------------------------------------------------------
// Exclusive scan over the 586 bucket counts (single block, 1 elem/thread).
// ---------------------------------------------------------------------------
__global__ __launch_bounds__(1024) void bucket_scan(const int* __restrict__ bcnt,
                                                    int* __restrict__ boffs,
                                                    int* __restrict__ gtails, int nnz) {
    __shared__ int s[1024];
    int t = threadIdx.x;
    int x = (t < NBUCK) ? bcnt[t] : 0;
    s[t] = x;
    __syncthreads();
#pragma unroll
    for (int off = 1; off < 1024; off <<= 1) {
        int v = (t >= off) ? s[t - off] : 0;
        __syncthreads();
        s[t] += v;
        __syncthreads();
    }
    if (t < NBUCK) {
        int e = s[t] - x;
        boffs[t] = e;
        gtails[t] = e;
    }
    if (t == 0) boffs[NBUCK] = nnz;
}

// ---------------------------------------------------------------------------
// LDS-staged multisplit into 256-row buckets (round-15 proven).
// pv payload: .x = (r_local<<18) | col  (rl<256, col<2^18), .y = val
// ---------------------------------------------------------------------------
__global__ __launch_bounds__(1024) void coarse_multisplit(const int* __restrict__ rows,
                                                          const int* __restrict__ cols,
                                                          const float* __restrict__ vals,
                                                          int* __restrict__ gtails,
                                                          int2* __restrict__ pv, int nnz) {
    extern __shared__ int dyn[];
    int2* stage = (int2*)dyn;          // [EPB]  bucket-sorted payloads (75 KB)
    int*  smap  = dyn + 2 * EPB;       // [EPB]  per-slot dst shift (37.5 KB)
    __shared__ int hcnt[NBUCK];        // counts -> then local bump cursors
    __shared__ int lstart[NBUCK];      // local exclusive prefix (immutable)
    __shared__ int shiftv[NBUCK];      // global base - local start

    int tid = threadIdx.x;
    int e0 = blockIdx.x * EPB;
    int e1 = e0 + EPB < nnz ? e0 + EPB : nnz;
    int nE = e1 - e0;

    // phase 1: local histogram
    for (int i = tid; i < NBUCK; i += 1024) hcnt[i] = 0;
    __syncthreads();
    for (int i = e0 + tid; i < e1; i += 1024)
        atomicAdd(&hcnt[rows[i] >> BSHIFT], 1);
    __syncthreads();

    // phase 2: local scan (Hillis-Steele over 1024 slots; smap[0:1024) scratch)
    int cnt = (tid < NBUCK) ? hcnt[tid] : 0;
    smap[tid] = cnt;
    __syncthreads();
#pragma unroll
    for (int off = 1; off < 1024; off <<= 1) {
        int v = (tid >= off) ? smap[tid - off] : 0;
        __syncthreads();
        smap[tid] += v;
        __syncthreads();
    }
    if (tid < NBUCK) {
        int ls = smap[tid] - cnt;      // exclusive local prefix
        lstart[tid] = ls;
        hcnt[tid] = ls;                // init bump cursor
        int gb = cnt ? atomicAdd(&gtails[tid], cnt) : 0;  // global base
        shiftv[tid] = gb - ls;
    }
    __syncthreads();

    // phase 3: fill per-slot shift map (avg 14, bounded run per bucket)
    for (int b = tid; b < NBUCK; b += 1024) {
        int beg = lstart[b];
        int end_ = (b == NBUCK - 1) ? nE : lstart[b + 1];
        int sh = shiftv[b];
        for (int k = beg; k < end_; ++k) smap[k] = sh;
    }
    __syncthreads();

    // phase 4: placement into bucket-sorted LDS slots (rows re-read: L2-warm)
    for (int i = e0 + tid; i < e1; i += 1024) {
        int r = rows[i];
        int p = atomicAdd(&hcnt[r >> BSHIFT], 1);
        stage[p] = make_int2(((r & 255) << 18) | cols[i], __float_as_int(vals[i]));
    }
    __syncthreads();

    // phase 5: coalesced flush (consecutive lanes -> consecutive dst per run)
    for (int j = tid; j < nE; j += 1024)
        pv[smap[j] + j] = stage[j];
}

// ---------------------------------------------------------------------------
// Fine scatter within a 256-row bucket + row_ptr production.
// ---------------------------------------------------------------------------
__global__ __launch_bounds__(1024) void fine_scatter(const int* __restrict__ boffs,
                                                     const int2* __restrict__ pv,
                                                     int2* __restrict__ packed,
                                                     int* __restrict__ row_ptr, int nnz) {
    __shared__ int rcnt[256];
    __shared__ int loff[256];
    int b = blockIdx.x;
    int tid = threadIdx.x;
    int lo = boffs[b], hi = boffs[b + 1];
    int r0 = b << BSHIFT;
    int nr = N_NODES - r0; if (nr > 256) nr = 256;

    if (tid < 256) rcnt[tid] = 0;
    __syncthreads();
    for (int i = lo + tid; i < hi; i += 1024)
        atomicAdd(&rcnt[pv[i].x >> 18], 1);
    __syncthreads();
    if (tid < 256) loff[tid] = rcnt[tid];
    __syncthreads();
#pragma unroll
    for (int off = 1; off < 256; off <<= 1) {
        int v = (tid < 256 && tid >= off) ? loff[tid - off] : 0;
        __syncthreads();
        if (tid < 256) loff[tid] += v;
        __syncthreads();
    }
    if (tid < 256) {
        int e = lo + loff[tid] - rcnt[tid];    // exclusive prefix + bucket base
        loff[tid] = e;
        if (tid < nr) row_ptr[r0 + tid] = e;
    }
    if (b == 0 && tid == 0) row_ptr[N_NODES] = nnz;
    __syncthreads();
    for (int i = lo + tid; i < hi; i += 1024) {
        int2 e = pv[i];
        int rl = e.x >> 18;
        int pos = atomicAdd(&loff[rl], 1);
        packed[pos] = make_int2(e.x & 0x3FFFF, e.y);
    }
}

// ---------------------------------------------------------------------------
// Layer-1 table GEMM (round-2 proven LDS version).
// ---------------------------------------------------------------------------
__global__ __launch_bounds__(256) void gemm_table_f32(const float* __restrict__ uE,
                                                      const float* __restrict__ iE,
                                                      const float* __restrict__ W,
                                                      unsigned short* __restrict__ Zh,
                                                      int n_rows) {
    __shared__ float Wl[64 * 64];        // 16 KB
    __shared__ float Xf[64 * 64];        // 16 KB
    int tid = threadIdx.x;
    int lane = tid & 63;
    int wave = tid >> 6;
    int r0 = blockIdx.x * 64;
    int last = n_rows - 1;

    for (int i = tid; i < 64 * 64; i += 256) Wl[i] = W[i];
    for (int i = tid; i < 64 * 16; i += 256) {       // 1024 float4
        int row = i >> 4, q = i & 15;
        int r = r0 + row; r = r > last ? last : r;
        const float4* src = (r < NUM_USERS)
            ? (const float4*)(uE + (size_t)r * 64)
            : (const float4*)(iE + (size_t)(r - NUM_USERS) * 64);
        ((float4*)Xf)[i] = src[q];
    }
    __syncthreads();

    int rbase = wave * 16;
    float acc[16];
#pragma unroll
    for (int i = 0; i < 16; ++i) acc[i] = 0.f;

#pragma unroll 1
    for (int kc = 0; kc < 16; ++kc) {    // 4 k-values per chunk
        float w0 = Wl[(kc * 4 + 0) * 64 + lane];
        float w1 = Wl[(kc * 4 + 1) * 64 + lane];
        float w2 = Wl[(kc * 4 + 2) * 64 + lane];
        float w3 = Wl[(kc * 4 + 3) * 64 + lane];
#pragma unroll
        for (int i = 0; i < 16; ++i) {
            float4 q = ((const float4*)Xf)[(rbase + i) * 16 + kc];  // LDS broadcast
            acc[i] = fmaf(q.x, w0, acc[i]);
            acc[i] = fmaf(q.y, w1, acc[i]);
            acc[i] = fmaf(q.z, w2, acc[i]);
            acc[i] = fmaf(q.w, w3, acc[i]);
        }
    }
#pragma unroll
    for (int i = 0; i < 16; ++i) {
        int r = r0 + rbase + i;
        if (r < n_rows) Zh[(size_t)r * 64 + lane] = f2bf(acc[i]);
    }
}

// ---------------------------------------------------------------------------
// Layer-2 table GEMM (round-2 proven LDS version; FALLBACK only — used when
// the workspace can't hold the fused Zh2 buffer).
// ---------------------------------------------------------------------------
__global__ __launch_bounds__(256) void gemm_table_bf16(const unsigned* __restrict__ Xh,
                                                       const float* __restrict__ W,
                                                       unsigned short* __restrict__ Zh,
                                                       int n_rows) {
    __shared__ float Wl[64 * 64];        // 16 KB
    __shared__ uint4 Xl4[64 * 8];        // 8 KB: 64 rows x 32 uints (bf16x2)
    int tid = threadIdx.x;
    int lane = tid & 63;
    int wave = tid >> 6;
    int r0 = blockIdx.x * 64;
    int nr = n_rows - r0; if (nr > 64) nr = 64;

    for (int i = tid; i < 64 * 64; i += 256) Wl[i] = W[i];
    const uint4* Xg4 = (const uint4*)(Xh + (size_t)r0 * 32);
    for (int i = tid; i < nr * 8; i += 256) Xl4[i] = Xg4[i];
    __syncthreads();

    const unsigned* Xl = (const unsigned*)Xl4;
    int rbase = wave * 16;
    float acc[16];
#pragma unroll
    for (int i = 0; i < 16; ++i) acc[i] = 0.f;

#pragma unroll 1
    for (int kc = 0; kc < 8; ++kc) {     // 8 k-values per chunk
        float w0 = Wl[(kc * 8 + 0) * 64 + lane];
        float w1 = Wl[(kc * 8 + 1) * 64 + lane];
        float w2 = Wl[(kc * 8 + 2) * 64 + lane];
        float w3 = Wl[(kc * 8 + 3) * 64 + lane];
        float w4 = Wl[(kc * 8 + 4) * 64 + lane];
        float w5 = Wl[(kc * 8 + 5) * 64 + lane];
        float w6 = Wl[(kc * 8 + 6) * 64 + lane];
        float w7 = Wl[(kc * 8 + 7) * 64 + lane];
#pragma unroll
        for (int i = 0; i < 16; ++i) {
            uint4 q = *(const uint4*)&Xl[(rbase + i) * 32 + kc * 4];  // broadcast
            acc[i] = fmaf(bflo(q.x), w0, acc[i]);
            acc[i] = fmaf(bfhi(q.x), w1, acc[i]);
            acc[i] = fmaf(bflo(q.y), w2, acc[i]);
            acc[i] = fmaf(bfhi(q.y), w3, acc[i]);
            acc[i] = fmaf(bflo(q.z), w4, acc[i]);
            acc[i] = fmaf(bfhi(q.z), w5, acc[i]);
            acc[i] = fmaf(bflo(q.w), w6, acc[i]);
            acc[i] = fmaf(bfhi(q.w), w7, acc[i]);
        }
    }
#pragma unroll
    for (int i = 0; i < 16; ++i) {
        int r = r0 + rbase + i;
        if (r < n_rows) Zh[(size_t)r * 64 + lane] = f2bf(acc[i]);
    }
}

// ---------------------------------------------------------------------------
// SPMM + bias + relu (round-2 proven, 1 row/wave) — used for layer 2.
// ---------------------------------------------------------------------------
__global__ __launch_bounds__(256) void spmm_bias_relu(const int* __restrict__ row_ptr,
                                                      const int2* __restrict__ packed,
                                                      const uint2* __restrict__ zh2,   // bf16x4, 16/row
                                                      const float* __restrict__ bias,  // [64] fp32
                                                      uint2* __restrict__ outh2,       // bf16x4, 16/row
                                                      int n_rows) {
    int tid = threadIdx.x;
    int lane = tid & 63;
    int wave = tid >> 6;
    int q = lane >> 4;                 // 0..3 quarter
    int k = lane & 15;                 // column group (4 cols per lane)
    int r = blockIdx.x * 4 + wave;
    if (r >= n_rows) return;

    uint2 su = zh2[(size_t)r * 16 + k];
    float4 acc;
    acc.x = q ? 0.f : bflo(su.x);
    acc.y = q ? 0.f : bfhi(su.x);
    acc.z = q ? 0.f : bflo(su.y);
    acc.w = q ? 0.f : bfhi(su.y);

    int e = row_ptr[r] + q;
    int end = row_ptr[r + 1];
    for (; e + 13 < end; e += 16) {    // 16 edges/iter (4 per quarter)
        int2 p0 = packed[e + 0];
        int2 p1 = packed[e + 4];
        int2 p2 = packed[e + 8];
        int2 p3 = packed[e + 12];
        uint2 z0 = zh2[(size_t)p0.x * 16 + k];
        uint2 z1 = zh2[(size_t)p1.x * 16 + k];
        uint2 z2 = zh2[(size_t)p2.x * 16 + k];
        uint2 z3 = zh2[(size_t)p3.x * 16 + k];
        float v0 = __int_as_float(p0.y), v1 = __int_as_float(p1.y);
        float v2 = __int_as_float(p2.y), v3 = __int_as_float(p3.y);
        acc.x = fmaf(v0, bflo(z0.x), acc.x); acc.y = fmaf(v0, bfhi(z0.x), acc.y);
        acc.z = fmaf(v0, bflo(z0.y), acc.z); acc.w = fmaf(v0, bfhi(z0.y), acc.w);
        acc.x = fmaf(v1, bflo(z1.x), acc.x); acc.y = fmaf(v1, bfhi(z1.x), acc.y);
        acc.z = fmaf(v1, bflo(z1.y), acc.z); acc.w = fmaf(v1, bfhi(z1.y), acc.w);
        acc.x = fmaf(v2, bflo(z2.x), acc.x); acc.y = fmaf(v2, bfhi(z2.x), acc.y);
        acc.z = fmaf(v2, bflo(z2.y), acc.z); acc.w = fmaf(v2, bfhi(z2.y), acc.w);
        acc.x = fmaf(v3, bflo(z3.x), acc.x); acc.y = fmaf(v3, bfhi(z3.x), acc.y);
        acc.z = fmaf(v3, bflo(z3.y), acc.z); acc.w = fmaf(v3, bfhi(z3.y), acc.w);
    }
    for (; e < end; e += 4) {
        int2 p = packed[e];
        uint2 z = zh2[(size_t)p.x * 16 + k];
        float v = __int_as_float(p.y);
        acc.x = fmaf(v, bflo(z.x), acc.x); acc.y = fmaf(v, bfhi(z.x), acc.y);
        acc.z = fmaf(v, bflo(z.y), acc.z); acc.w = fmaf(v, bfhi(z.y), acc.w);
    }

    acc.x += __shfl_xor(acc.x, 16, 64);
    acc.y += __shfl_xor(acc.y, 16, 64);
    acc.z += __shfl_xor(acc.z, 16, 64);
    acc.w += __shfl_xor(acc.w, 16, 64);
    acc.x += __shfl_xor(acc.x, 32, 64);
    acc.y += __shfl_xor(acc.y, 32, 64);
    acc.z += __shfl_xor(acc.z, 32, 64);
    acc.w += __shfl_xor(acc.w, 32, 64);
    if (q == 0) {
        float4 bv = ((const float4*)bias)[k];
        float a = fmaxf(acc.x + bv.x, 0.f);
        float b = fmaxf(acc.y + bv.y, 0.f);
        float c = fmaxf(acc.z + bv.z, 0.f);
        float d = fmaxf(acc.w + bv.w, 0.f);
        outh2[(size_t)r * 16 + k] = make_uint2(
            ((unsigned)f2bf(b) << 16) | (unsigned)f2bf(a),
            ((unsigned)f2bf(d) << 16) | (unsigned)f2bf(c));
    }
}

// ---------------------------------------------------------------------------
// Layer-1 SPMM + fused Z2 epilogue, round-22 restructure of round-21:
//  * round-21 failure diagnosed from counters: VGPR=60 (compiler SANK the W
//    loads into the row loop to chase occupancy -> 64 cache loads/row) and
//    Occupancy=33% (16 rows/wave -> only 9376 waves, tail-starved).
//  * fix 1: __launch_bounds__(256,3) + "+v" keep-alive asm pins the 64-value
//    W column in VGPRs (reload becomes unsound for the compiler).
//  * fix 2: 4 rows/wave -> 9375 blocks / 37500 waves (same wave count as the
//    proven 1-row spmm); W load amortized x4 and L1-resident (16 KB).
// Epilogue math unchanged from round-21 (correctness-proven, bit-identical
// to gemm_table_bf16: j ascending 0..63).
// ---------------------------------------------------------------------------
__global__ __launch_bounds__(256, 3) void spmm_bias_relu_z(
        const int* __restrict__ row_ptr,
        const int2* __restrict__ packed,
        const uint2* __restrict__ zh2,
        const float* __restrict__ bias,
        uint2* __restrict__ outh2,
        const float* __restrict__ Wz,
        unsigned short* __restrict__ Zh_out,
        int n_rows) {
    int tid = threadIdx.x;
    int lane = tid & 63;
    int wave = tid >> 6;
    int q = lane >> 4;                 // 0..3 quarter
    int k = lane & 15;                 // column group (4 cols per lane)

    // W column in VGPRs, once per wave; keep-alive pins residency.
    float wreg[64];
#pragma unroll
    for (int j = 0; j < 64; ++j) wreg[j] = Wz[j * 64 + lane];
#pragma unroll
    for (int j = 0; j < 64; ++j) asm volatile("" : "+v"(wreg[j]));

    float4 bv = ((const float4*)bias)[k];
    int rbase = (blockIdx.x * 4 + wave) * 4;   // 4 rows per wave

#pragma unroll 1
    for (int ii = 0; ii < 4; ++ii) {
        int r = rbase + ii;
        if (r >= n_rows) break;        // wave-uniform (never taken: exact grid)

        uint2 su = zh2[(size_t)r * 16 + k];
        float4 acc;
        acc.x = q ? 0.f : bflo(su.x);
        acc.y = q ? 0.f : bfhi(su.x);
        acc.z = q ? 0.f : bflo(su.y);
        acc.w = q ? 0.f : bfhi(su.y);

        int e = row_ptr[r] + q;
        int end = row_ptr[r + 1];
        for (; e + 13 < end; e += 16) {    // 16 edges/iter (4 per quarter)
            int2 p0 = packed[e + 0];
            int2 p1 = packed[e + 4];
            int2 p2 = packed[e + 8];
            int2 p3 = packed[e + 12];
            uint2 z0 = zh2[(size_t)p0.x * 16 + k];
            uint2 z1 = zh2[(size_t)p1.x * 16 + k];
            uint2 z2 = zh2[(size_t)p2.x * 16 + k];
            uint2 z3 = zh2[(size_t)p3.x * 16 + k];
            float v0 = __int_as_float(p0.y), v1 = __int_as_float(p1.y);
            float v2 = __int_as_float(p2.y), v3 = __int_as_float(p3.y);
            acc.x = fmaf(v0, bflo(z0.x), acc.x); acc.y = fmaf(v0, bfhi(z0.x), acc.y);
            acc.z = fmaf(v0, bflo(z0.y), acc.z); acc.w = fmaf(v0, bfhi(z0.y), acc.w);
            acc.x = fmaf(v1, bflo(z1.x), acc.x); acc.y = fmaf(v1, bfhi(z1.x), acc.y);
            acc.z = fmaf(v1, bflo(z1.y), acc.z); acc.w = fmaf(v1, bfhi(z1.y), acc.w);
            acc.x = fmaf(v2, bflo(z2.x), acc.x); acc.y = fmaf(v2, bfhi(z2.x), acc.y);
            acc.z = fmaf(v2, bflo(z2.y), acc.z); acc.w = fmaf(v2, bfhi(z2.y), acc.w);
            acc.x = fmaf(v3, bflo(z3.x), acc.x); acc.y = fmaf(v3, bfhi(z3.x), acc.y);
            acc.z = fmaf(v3, bflo(z3.y), acc.z); acc.w = fmaf(v3, bfhi(z3.y), acc.w);
        }
        for (; e < end; e += 4) {
            int2 p = packed[e];
            uint2 z = zh2[(size_t)p.x * 16 + k];
            float v = __int_as_float(p.y);
            acc.x = fmaf(v, bflo(z.x), acc.x); acc.y = fmaf(v, bfhi(z.x), acc.y);
            acc.z = fmaf(v, bflo(z.y), acc.z); acc.w = fmaf(v, bfhi(z.y), acc.w);
        }

        acc.x += __shfl_xor(acc.x, 16, 64);
        acc.y += __shfl_xor(acc.y, 16, 64);
        acc.z += __shfl_xor(acc.z, 16, 64);
        acc.w += __shfl_xor(acc.w, 16, 64);
        acc.x += __shfl_xor(acc.x, 32, 64);
        acc.y += __shfl_xor(acc.y, 32, 64);
        acc.z += __shfl_xor(acc.z, 32, 64);
        acc.w += __shfl_xor(acc.w, 32, 64);

        // bias+relu+round on ALL lanes (quarters hold identical sums)
        float a = fmaxf(acc.x + bv.x, 0.f);
        float b = fmaxf(acc.y + bv.y, 0.f);
        float c = fmaxf(acc.z + bv.z, 0.f);
        float d = fmaxf(acc.w + bv.w, 0.f);
        int pa = (int)(((unsigned)f2bf(b) << 16) | (unsigned)f2bf(a));
        int pb = (int)(((unsigned)f2bf(d) << 16) | (unsigned)f2bf(c));
        if (q == 0)
            outh2[(size_t)r * 16 + k] = make_uint2((unsigned)pa, (unsigned)pb);

        // Z2[r][lane] = sum_j row[j]*Wz[j][lane], j ascending — zero DS:
        // readlane(imm) -> SGPR broadcast, FMA against VGPR-resident W col.
        float z = 0.f;
#pragma unroll
        for (int jj = 0; jj < 16; ++jj) {
            unsigned ua = (unsigned)__builtin_amdgcn_readlane(pa, jj);
            unsigned ub = (unsigned)__builtin_amdgcn_readlane(pb, jj);
            z = fmaf(bflo(ua), wreg[4 * jj + 0], z);
            z = fmaf(bfhi(ua), wreg[4 * jj + 1], z);
            z = fmaf(bflo(ub), wreg[4 * jj + 2], z);
            z = fmaf(bfhi(ub), wreg[4 * jj + 3], z);
        }
        Zh_out[(size_t)r * 64 + lane] = f2bf(z);
    }
}

// ---------------------------------------------------------------------------
// Fused MLP (round-16 proven: 1024 threads/block, 16 waves/CU, 4 rows/wave).
// ---------------------------------------------------------------------------
__global__ __launch_bounds__(1024) void fused_mlp(
        const int* __restrict__ userIdx, const int* __restrict__ itemIdx,
        const float* __restrict__ uEmb, const float* __restrict__ iEmb,
        const unsigned short* __restrict__ feat1h,
        const unsigned short* __restrict__ feat2h,
        const float* __restrict__ W1, const float* __restrict__ b1,
        const float* __restrict__ W2, const float* __restrict__ b2,
        const float* __restrict__ W3, const float* __restrict__ b3,
        float* __restrict__ out) {
    __shared__ float    Wl[128 * 64];   // 32 KB  W1 chunk
    __shared__ unsigned El[64 * 64];    // 16 KB  E tile (bf16x2)
    __shared__ float    Ht[64 * 64];    // 16 KB  relu(E@W1+b1) tile
    __shared__ float    W2l[64 * 32];   // 8 KB
    __shared__ float    w3l[32];
    __shared__ float    b2l[32];
    __shared__ int      uidx[64], iidx[64];
    int tid = threadIdx.x;
    int lane = tid & 63;
    int wave = tid >> 6;                // 0..15
    int r0 = blockIdx.x * 64;
    int rbase = wave * 4;               // 4 rows per wave

    if (tid < 64) uidx[tid] = userIdx[r0 + tid];
    else if (tid < 128) iidx[tid - 64] = itemIdx[r0 + tid - 64];
    if (tid < 32) { w3l[tid] = W3[tid]; b2l[tid] = b2[tid]; }
    for (int i = tid; i < 64 * 32; i += 1024) W2l[i] = W2[i];

    float acc[4];
    float bv = b1[lane];
#pragma unroll
    for (int i = 0; i < 4; ++i) acc[i] = bv;

#pragma unroll 1
    for (int c = 0; c < 3; ++c) {
        __syncthreads();   // idx ready (c=0); El/Wl reuse safe (c>0)
        for (int i = tid; i < 128 * 64; i += 1024) Wl[i] = W1[c * 128 * 64 + i];
        {   // E-tile build: 1024 work items == 1024 threads (one gather each)
            int t = tid;                          // 64 rows x 2 segs x 8 quads
            int row = t >> 4;
            int seg = (t >> 3) & 1;
            int q   = t & 7;
            int gseg = c * 2 + seg;               // 0..5
            uint4 val;
            if (gseg == 0 || gseg == 3) {         // fp32 embedding segment
                const float* p = (gseg == 0)
                    ? uEmb + (size_t)uidx[row] * 64 + q * 8
                    : iEmb + (size_t)iidx[row] * 64 + q * 8;
                float4 a = *(const float4*)p;
                float4 b = *(const float4*)(p + 4);
                val.x = ((unsigned)f2bf(a.y) << 16) | f2bf(a.x);
                val.y = ((unsigned)f2bf(a.w) << 16) | f2bf(a.z);
                val.z = ((unsigned)f2bf(b.y) << 16) | f2bf(b.x);
                val.w = ((unsigned)f2bf(b.w) << 16) | f2bf(b.z);
            } else {
                const unsigned short* src;
                if (gseg == 1)      src = feat1h + (size_t)uidx[row] * 64;
                else if (gseg == 2) src = feat2h + (size_t)uidx[row] * 64;
                else if (gseg == 4) src = feat1h + (size_t)(iidx[row] + NUM_USERS) * 64;
                else                src = feat2h + (size_t)(iidx[row] + NUM_USERS) * 64;
                val = *(const uint4*)(src + q * 8);
            }
            *(uint4*)&El[row * 64 + seg * 32 + q * 4] = val;
        }
        __syncthreads();
        const uint4* El4 = (const uint4*)El;
#pragma unroll 1
        for (int k = 0; k < 128; k += 8) {
            float w0 = Wl[(k + 0) * 64 + lane];
            float w1 = Wl[(k + 1) * 64 + lane];
            float w2 = Wl[(k + 2) * 64 + lane];
            float w3 = Wl[(k + 3) * 64 + lane];
            float w4 = Wl[(k + 4) * 64 + lane];
            float w5 = Wl[(k + 5) * 64 + lane];
            float w6 = Wl[(k + 6) * 64 + lane];
            float w7 = Wl[(k + 7) * 64 + lane];
#pragma unroll
            for (int i = 0; i < 4; ++i) {
                uint4 q = El4[(rbase + i) * 16 + (k >> 3)];   // LDS broadcast
                acc[i] = fmaf(bflo(q.x), w0, acc[i]);
                acc[i] = fmaf(bfhi(q.x), w1, acc[i]);
                acc[i] = fmaf(bflo(q.y), w2, acc[i]);
                acc[i] = fmaf(bfhi(q.y), w3, acc[i]);
                acc[i] = fmaf(bflo(q.z), w4, acc[i]);
                acc[i] = fmaf(bfhi(q.z), w5, acc[i]);
                acc[i] = fmaf(bflo(q.w), w6, acc[i]);
                acc[i] = fmaf(bfhi(q.w), w7, acc[i]);
            }
        }
    }

    // H-tile: relu
#pragma unroll
    for (int i = 0; i < 4; ++i) Ht[(rbase + i) * 64 + lane] = fmaxf(acc[i], 0.f);
    __syncthreads();

    // W2/W3 finish: half-wave per row (lanes k<32 = W2 cols), shfl reduce
    int half = lane >> 5;
    int k = lane & 31;
    float b3v = b3[0];
#pragma unroll 1
    for (int p = 0; p < 2; ++p) {
        int row = rbase + p * 2 + half;
        float z = b2l[k];
#pragma unroll
        for (int j = 0; j < 64; ++j)
            z = fmaf(Ht[row * 64 + j], W2l[j * 32 + k], z);
        z *= w3l[k];
#pragma unroll
        for (int off = 16; off; off >>= 1)
            z += __shfl_xor(z, off, 64);
        if (k == 0) out[r0 + row] = z + b3v;
    }
}

// ---------------------------------------------------------------------------
extern "C" void kernel_launch(void* const* d_in, const int* in_sizes, int n_in,
                              void* d_out, int out_size, void* d_ws, size_t ws_size,
                              hipStream_t stream) {
    const int*   userIdx = (const int*)  d_in[0];
    const int*   itemIdx = (const int*)  d_in[1];
    const int*   lap_rows= (const int*)  d_in[2];
    const int*   lap_cols= (const int*)  d_in[3];
    const float* lap_vals= (const float*)d_in[4];
    const float* uEmb    = (const float*)d_in[5];
    const float* iEmb    = (const float*)d_in[6];
    const float* gW0     = (const float*)d_in[7];
    const float* gb0     = (const float*)d_in[8];
    const float* gW1     = (const float*)d_in[9];
    const float* gb1     = (const float*)d_in[10];
    const float* W1      = (const float*)d_in[11];
    const float* b1      = (const float*)d_in[12];
    const float* W2      = (const float*)d_in[13];
    const float* b2      = (const float*)d_in[14];
    const float* W3      = (const float*)d_in[15];
    const float* b3      = (const float*)d_in[16];
    float* out = (float*)d_out;

    const size_t NF = (size_t)N_NODES * EMB;              // 9.6M elements
    char* w = (char*)d_ws;
    unsigned short* bufA = (unsigned short*)w;            // feat1h (19.2 MB)
    unsigned short* bufB = bufA + NF;                     // feat2h (19.2 MB)
    char*  region3 = (char*)(bufB + NF);                  // 38.4 MB multi-use
    // region3 first half: pv during CSR build, then Zh (layer-1 Z)
    int2*  pv      = (int2*)region3;                      // 19.2 MB (dead after fine_scatter)
    unsigned short* Zh = (unsigned short*)region3;        // Z1 table (19.2 MB)
    // region3 second half: packed lives through both spmm calls
    int2*  packed  = (int2*)(region3 + NF * sizeof(float)); // 19.2 MB
    int*   row_ptr = (int*)(packed + NNZ);                // N_NODES+1
    int*   boffs   = row_ptr + (N_NODES + 1);             // NBUCK+1 (immutable)
    int*   gtails  = boffs + (NBUCK + 1);                 // NBUCK (mutable tails)
    int*   bcnt    = gtails + NBUCK;                      // NBUCK
    // Z2 table at workspace tail (spmm1 reads Z1 while writing Z2 -> distinct)
    size_t tail_off = ((size_t)((char*)(bcnt + NBUCK) - w) + 15) & ~(size_t)15;
    unsigned short* Zh2 = (unsigned short*)(w + tail_off);
    bool fuse = (tail_off + NF * sizeof(unsigned short)) <= ws_size;

    const int ms_grid   = (NNZ + EPB - 1) / EPB;          // 256 (1 block/CU)
    const int ms_lds    = EPB * 12;                       // stage (8B) + smap (4B)
    const int spmm_grid = (N_NODES + 3) / 4;              // 37500 (1 row/wave)
    const int spmmz_grid= (N_NODES + 15) / 16;            // 9375 (4 rows/wave)
    const int gemm_grid = (N_NODES + 63) / 64;            // 2344

    // ---- Build bucketed CSR (shared by both layers) — round-2 pipeline
    hipMemsetAsync(bcnt, 0, NBUCK * sizeof(int), stream);
    bucket_hist<<<256, 1024, 0, stream>>>(lap_rows, bcnt, NNZ);
    bucket_scan<<<1, 1024, 0, stream>>>(bcnt, boffs, gtails, NNZ);
    coarse_multisplit<<<ms_grid, 1024, ms_lds, stream>>>(lap_rows, lap_cols, lap_vals,
                                                         gtails, pv, NNZ);
    fine_scatter<<<NBUCK, 1024, 0, stream>>>(boffs, pv, packed, row_ptr, NNZ);

    // ---- Layer 1: Z1 = concat(uEmb,iEmb)@gW0 ; feat1 = relu((L+I)Z1 + gb0)
    gemm_table_f32<<<gemm_grid, 256, 0, stream>>>(uEmb, iEmb, gW0, Zh, N_NODES);

    if (fuse) {
        // spmm1 + fused Z2 (pinned-VGPR readlane epilogue) — deletes gemm_table_bf16
        spmm_bias_relu_z<<<spmmz_grid, 256, 0, stream>>>(row_ptr, packed,
            (const uint2*)Zh, gb0, (uint2*)bufA, gW1, Zh2, N_NODES);
        spmm_bias_relu<<<spmm_grid, 256, 0, stream>>>(row_ptr, packed,
            (const uint2*)Zh2, gb1, (uint2*)bufB, N_NODES);
    } else {
        // fallback: original 3-kernel middle section
        spmm_bias_relu<<<spmm_grid, 256, 0, stream>>>(row_ptr, packed,
            (const uint2*)Zh, gb0, (uint2*)bufA, N_NODES);
        gemm_table_bf16<<<gemm_grid, 256, 0, stream>>>((const unsigned*)bufA, gW1,
                                                       Zh, N_NODES);
        spmm_bias_relu<<<spmm_grid, 256, 0, stream>>>(row_ptr, packed,
            (const uint2*)Zh, gb1, (uint2*)bufB, N_NODES);
    }

    // ---- Fused MLP: gather + E@W1+b1+relu + @W2+b2 + @W3+b3
    fused_mlp<<<BATCH / 64, 1024, 0, stream>>>(userIdx, itemIdx, uEmb, iEmb,
                                               bufA, bufB, W1, b1, W2, b2, W3, b3, out);
}

// Round 9
// 459.341 us; speedup vs baseline: 1.0946x; 1.0746x over previous
//
#include <hip/hip_runtime.h>
#include <hip/hip_bf16.h>

// Problem constants (from reference)
#define NUM_USERS 100000
#define NUM_ITEMS 50000
#define N_NODES   150000   // NUM_USERS + NUM_ITEMS
#define EMB       64
#define NNZ       2400000
#define BATCH     16384
#define D_CAT     384      // EMB*3*2
#define BSHIFT    8        // 256 rows per bucket: multisplit segment ~2 lines
#define NBUCK     ((N_NODES + 255) >> 8)   // 586
#define EPB       9375     // edges per multisplit block -> grid = exactly 256

// ---- bf16 helpers (bit-level, RN-even for f32->bf16) -----------------------
__device__ __forceinline__ unsigned short f2bf(float f) {
    unsigned u = __float_as_uint(f);
    unsigned r = u + 0x7fffu + ((u >> 16) & 1u);
    return (unsigned short)(r >> 16);
}
__device__ __forceinline__ float bflo(unsigned u) { return __uint_as_float(u << 16); }
__device__ __forceinline__ float bfhi(unsigned u) { return __uint_as_float(u & 0xffff0000u); }

// ---------------------------------------------------------------------------
// Bucket histogram, LDS-aggregated (round-2 proven: 256 blocks).
// ---------------------------------------------------------------------------
__global__ __launch_bounds__(1024) void bucket_hist(const int* __restrict__ rows,
                                                    int* __restrict__ bcnt, int nnz) {
    __shared__ int h[NBUCK];
    int tid = threadIdx.x;
    for (int i = tid; i < NBUCK; i += 1024) h[i] = 0;
    __syncthreads();
    for (int i = blockIdx.x * 1024 + tid; i < nnz; i += gridDim.x * 1024)
        atomicAdd(&h[rows[i] >> BSHIFT], 1);
    __syncthreads();
    for (int i = tid; i < NBUCK; i += 1024) {
        int c = h[i];
        if (c) atomicAdd(&bcnt[i], c);
    }
}

// ---------------------------------------------------------------------------
// Exclusive scan over the 586 bucket counts (single block, 1 elem/thread).
// ---------------------------------------------------------------------------
__global__ __launch_bounds__(1024) void bucket_scan(const int* __restrict__ bcnt,
                                                    int* __restrict__ boffs,
                                                    int* __restrict__ gtails, int nnz) {
    __shared__ int s[1024];
    int t = threadIdx.x;
    int x = (t < NBUCK) ? bcnt[t] : 0;
    s[t] = x;
    __syncthreads();
#pragma unroll
    for (int off = 1; off < 1024; off <<= 1) {
        int v = (t >= off) ? s[t - off] : 0;
        __syncthreads();
        s[t] += v;
        __syncthreads();
    }
    if (t < NBUCK) {
        int e = s[t] - x;
        boffs[t] = e;
        gtails[t] = e;
    }
    if (t == 0) boffs[NBUCK] = nnz;
}

// ---------------------------------------------------------------------------
// LDS-staged multisplit into 256-row buckets (round-15 proven).
// pv payload: .x = (r_local<<18) | col  (rl<256, col<2^18), .y = val
// ---------------------------------------------------------------------------
__global__ __launch_bounds__(1024) void coarse_multisplit(const int* __restrict__ rows,
                                                          const int* __restrict__ cols,
                                                          const float* __restrict__ vals,
                                                          int* __restrict__ gtails,
                                                          int2* __restrict__ pv, int nnz) {
    extern __shared__ int dyn[];
    int2* stage = (int2*)dyn;          // [EPB]  bucket-sorted payloads (75 KB)
    int*  smap  = dyn + 2 * EPB;       // [EPB]  per-slot dst shift (37.5 KB)
    __shared__ int hcnt[NBUCK];        // counts -> then local bump cursors
    __shared__ int lstart[NBUCK];      // local exclusive prefix (immutable)
    __shared__ int shiftv[NBUCK];      // global base - local start

    int tid = threadIdx.x;
    int e0 = blockIdx.x * EPB;
    int e1 = e0 + EPB < nnz ? e0 + EPB : nnz;
    int nE = e1 - e0;

    // phase 1: local histogram
    for (int i = tid; i < NBUCK; i += 1024) hcnt[i] = 0;
    __syncthreads();
    for (int i = e0 + tid; i < e1; i += 1024)
        atomicAdd(&hcnt[rows[i] >> BSHIFT], 1);
    __syncthreads();

    // phase 2: local scan (Hillis-Steele over 1024 slots; smap[0:1024) scratch)
    int cnt = (tid < NBUCK) ? hcnt[tid] : 0;
    smap[tid] = cnt;
    __syncthreads();
#pragma unroll
    for (int off = 1; off < 1024; off <<= 1) {
        int v = (tid >= off) ? smap[tid - off] : 0;
        __syncthreads();
        smap[tid] += v;
        __syncthreads();
    }
    if (tid < NBUCK) {
        int ls = smap[tid] - cnt;      // exclusive local prefix
        lstart[tid] = ls;
        hcnt[tid] = ls;                // init bump cursor
        int gb = cnt ? atomicAdd(&gtails[tid], cnt) : 0;  // global base
        shiftv[tid] = gb - ls;
    }
    __syncthreads();

    // phase 3: fill per-slot shift map (avg 14, bounded run per bucket)
    for (int b = tid; b < NBUCK; b += 1024) {
        int beg = lstart[b];
        int end_ = (b == NBUCK - 1) ? nE : lstart[b + 1];
        int sh = shiftv[b];
        for (int k = beg; k < end_; ++k) smap[k] = sh;
    }
    __syncthreads();

    // phase 4: placement into bucket-sorted LDS slots (rows re-read: L2-warm)
    for (int i = e0 + tid; i < e1; i += 1024) {
        int r = rows[i];
        int p = atomicAdd(&hcnt[r >> BSHIFT], 1);
        stage[p] = make_int2(((r & 255) << 18) | cols[i], __float_as_int(vals[i]));
    }
    __syncthreads();

    // phase 5: coalesced flush (consecutive lanes -> consecutive dst per run)
    for (int j = tid; j < nE; j += 1024)
        pv[smap[j] + j] = stage[j];
}

// ---------------------------------------------------------------------------
// Fine scatter within a 256-row bucket + row_ptr production.
// ---------------------------------------------------------------------------
__global__ __launch_bounds__(1024) void fine_scatter(const int* __restrict__ boffs,
                                                     const int2* __restrict__ pv,
                                                     int2* __restrict__ packed,
                                                     int* __restrict__ row_ptr, int nnz) {
    __shared__ int rcnt[256];
    __shared__ int loff[256];
    int b = blockIdx.x;
    int tid = threadIdx.x;
    int lo = boffs[b], hi = boffs[b + 1];
    int r0 = b << BSHIFT;
    int nr = N_NODES - r0; if (nr > 256) nr = 256;

    if (tid < 256) rcnt[tid] = 0;
    __syncthreads();
    for (int i = lo + tid; i < hi; i += 1024)
        atomicAdd(&rcnt[pv[i].x >> 18], 1);
    __syncthreads();
    if (tid < 256) loff[tid] = rcnt[tid];
    __syncthreads();
#pragma unroll
    for (int off = 1; off < 256; off <<= 1) {
        int v = (tid < 256 && tid >= off) ? loff[tid - off] : 0;
        __syncthreads();
        if (tid < 256) loff[tid] += v;
        __syncthreads();
    }
    if (tid < 256) {
        int e = lo + loff[tid] - rcnt[tid];    // exclusive prefix + bucket base
        loff[tid] = e;
        if (tid < nr) row_ptr[r0 + tid] = e;
    }
    if (b == 0 && tid == 0) row_ptr[N_NODES] = nnz;
    __syncthreads();
    for (int i = lo + tid; i < hi; i += 1024) {
        int2 e = pv[i];
        int rl = e.x >> 18;
        int pos = atomicAdd(&loff[rl], 1);
        packed[pos] = make_int2(e.x & 0x3FFFF, e.y);
    }
}

// ---------------------------------------------------------------------------
// Layer-1 table GEMM, round-23 readlane/VALU rewrite.
// Pipe arithmetic (from r4/r7/r8 counters): the old LDS version issues ~256
// ds_read_b128 broadcasts/wave on the per-CU-SHARED DS pipe (~127K cyc/CU =
// ~53 us). This version uses NO LDS: lane l holds X[r][l] (coalesced global
// load); v_readlane(imm) -> SGPR -> FMA against a per-lane W column in 64
// VGPRs. 4096 VALU-cyc/wave spread over 4 SIMDs/CU => ~16 us model.
// W is the dense main operand (every FMA) so the compiler cannot profitably
// sink its loads (the r7/r8 failure mode). k ascending -> bit-identical.
// ---------------------------------------------------------------------------
__global__ __launch_bounds__(256, 3) void gemm_table_f32(const float* __restrict__ uE,
                                                         const float* __restrict__ iE,
                                                         const float* __restrict__ W,
                                                         unsigned short* __restrict__ Zh,
                                                         int n_rows) {
    int tid = threadIdx.x;
    int lane = tid & 63;
    int wave = tid >> 6;
    int r0 = blockIdx.x * 64 + wave * 16;
    int last = n_rows - 1;

    float wreg[64];
#pragma unroll
    for (int k = 0; k < 64; ++k) wreg[k] = W[k * 64 + lane];   // coalesced

    float x[16];
#pragma unroll
    for (int i = 0; i < 16; ++i) {
        int r = r0 + i; r = r > last ? last : r;
        x[i] = (r < NUM_USERS) ? uE[(size_t)r * 64 + lane]
                               : iE[(size_t)(r - NUM_USERS) * 64 + lane];
    }

#pragma unroll
    for (int i = 0; i < 16; ++i) {
        float acc = 0.f;
        int xb = __float_as_int(x[i]);
#pragma unroll
        for (int k = 0; k < 64; ++k) {
            float xv = __int_as_float(__builtin_amdgcn_readlane(xb, k));
            acc = fmaf(xv, wreg[k], acc);
        }
        int r = r0 + i;
        if (r < n_rows) Zh[(size_t)r * 64 + lane] = f2bf(acc);
    }
}

// ---------------------------------------------------------------------------
// Layer-2 table GEMM, round-23 readlane/VALU rewrite (bf16 input).
// Lane l (l&31) holds the uint pair (elems 2l,2l+1) of the row; 32 readlanes
// + 64 FMAs per row, unpack (shl/and) foldable to SALU. k ascending ->
// bit-identical to the old kernel.
// ---------------------------------------------------------------------------
__global__ __launch_bounds__(256, 3) void gemm_table_bf16(const unsigned* __restrict__ Xh,
                                                          const float* __restrict__ W,
                                                          unsigned short* __restrict__ Zh,
                                                          int n_rows) {
    int tid = threadIdx.x;
    int lane = tid & 63;
    int wave = tid >> 6;
    int r0 = blockIdx.x * 64 + wave * 16;
    int last = n_rows - 1;

    float wreg[64];
#pragma unroll
    for (int k = 0; k < 64; ++k) wreg[k] = W[k * 64 + lane];   // coalesced

    unsigned x[16];
#pragma unroll
    for (int i = 0; i < 16; ++i) {
        int r = r0 + i; r = r > last ? last : r;
        x[i] = Xh[(size_t)r * 32 + (lane & 31)];   // 2 bf16 per lane
    }

#pragma unroll
    for (int i = 0; i < 16; ++i) {
        float acc = 0.f;
#pragma unroll
        for (int j = 0; j < 32; ++j) {
            unsigned u = (unsigned)__builtin_amdgcn_readlane((int)x[i], j);
            acc = fmaf(bflo(u), wreg[2 * j + 0], acc);
            acc = fmaf(bfhi(u), wreg[2 * j + 1], acc);
        }
        int r = r0 + i;
        if (r < n_rows) Zh[(size_t)r * 64 + lane] = f2bf(acc);
    }
}

// ---------------------------------------------------------------------------
// SPMM + bias + relu (round-2 proven, 1 row/wave, 23 waves/CU) — BOTH layers.
// Round-8 lesson: this kernel is latency-bound and occupancy-critical; any
// fused epilogue that costs VGPRs throttles the gather by more than it saves
// (3 failed fusion attempts: +84, +46, +37 us). Do not touch.
// ---------------------------------------------------------------------------
__global__ __launch_bounds__(256) void spmm_bias_relu(const int* __restrict__ row_ptr,
                                                      const int2* __restrict__ packed,
                                                      const uint2* __restrict__ zh2,   // bf16x4, 16/row
                                                      const float* __restrict__ bias,  // [64] fp32
                                                      uint2* __restrict__ outh2,       // bf16x4, 16/row
                                                      int n_rows) {
    int tid = threadIdx.x;
    int lane = tid & 63;
    int wave = tid >> 6;
    int q = lane >> 4;                 // 0..3 quarter
    int k = lane & 15;                 // column group (4 cols per lane)
    int r = blockIdx.x * 4 + wave;
    if (r >= n_rows) return;

    uint2 su = zh2[(size_t)r * 16 + k];
    float4 acc;
    acc.x = q ? 0.f : bflo(su.x);
    acc.y = q ? 0.f : bfhi(su.x);
    acc.z = q ? 0.f : bflo(su.y);
    acc.w = q ? 0.f : bfhi(su.y);

    int e = row_ptr[r] + q;
    int end = row_ptr[r + 1];
    for (; e + 13 < end; e += 16) {    // 16 edges/iter (4 per quarter)
        int2 p0 = packed[e + 0];
        int2 p1 = packed[e + 4];
        int2 p2 = packed[e + 8];
        int2 p3 = packed[e + 12];
        uint2 z0 = zh2[(size_t)p0.x * 16 + k];
        uint2 z1 = zh2[(size_t)p1.x * 16 + k];
        uint2 z2 = zh2[(size_t)p2.x * 16 + k];
        uint2 z3 = zh2[(size_t)p3.x * 16 + k];
        float v0 = __int_as_float(p0.y), v1 = __int_as_float(p1.y);
        float v2 = __int_as_float(p2.y), v3 = __int_as_float(p3.y);
        acc.x = fmaf(v0, bflo(z0.x), acc.x); acc.y = fmaf(v0, bfhi(z0.x), acc.y);
        acc.z = fmaf(v0, bflo(z0.y), acc.z); acc.w = fmaf(v0, bfhi(z0.y), acc.w);
        acc.x = fmaf(v1, bflo(z1.x), acc.x); acc.y = fmaf(v1, bfhi(z1.x), acc.y);
        acc.z = fmaf(v1, bflo(z1.y), acc.z); acc.w = fmaf(v1, bfhi(z1.y), acc.w);
        acc.x = fmaf(v2, bflo(z2.x), acc.x); acc.y = fmaf(v2, bfhi(z2.x), acc.y);
        acc.z = fmaf(v2, bflo(z2.y), acc.z); acc.w = fmaf(v2, bfhi(z2.y), acc.w);
        acc.x = fmaf(v3, bflo(z3.x), acc.x); acc.y = fmaf(v3, bfhi(z3.x), acc.y);
        acc.z = fmaf(v3, bflo(z3.y), acc.z); acc.w = fmaf(v3, bfhi(z3.y), acc.w);
    }
    for (; e < end; e += 4) {
        int2 p = packed[e];
        uint2 z = zh2[(size_t)p.x * 16 + k];
        float v = __int_as_float(p.y);
        acc.x = fmaf(v, bflo(z.x), acc.x); acc.y = fmaf(v, bfhi(z.x), acc.y);
        acc.z = fmaf(v, bflo(z.y), acc.z); acc.w = fmaf(v, bfhi(z.y), acc.w);
    }

    acc.x += __shfl_xor(acc.x, 16, 64);
    acc.y += __shfl_xor(acc.y, 16, 64);
    acc.z += __shfl_xor(acc.z, 16, 64);
    acc.w += __shfl_xor(acc.w, 16, 64);
    acc.x += __shfl_xor(acc.x, 32, 64);
    acc.y += __shfl_xor(acc.y, 32, 64);
    acc.z += __shfl_xor(acc.z, 32, 64);
    acc.w += __shfl_xor(acc.w, 32, 64);
    if (q == 0) {
        float4 bv = ((const float4*)bias)[k];
        float a = fmaxf(acc.x + bv.x, 0.f);
        float b = fmaxf(acc.y + bv.y, 0.f);
        float c = fmaxf(acc.z + bv.z, 0.f);
        float d = fmaxf(acc.w + bv.w, 0.f);
        outh2[(size_t)r * 16 + k] = make_uint2(
            ((unsigned)f2bf(b) << 16) | (unsigned)f2bf(a),
            ((unsigned)f2bf(d) << 16) | (unsigned)f2bf(c));
    }
}

// ---------------------------------------------------------------------------
// Fused MLP (round-16 proven: 1024 threads/block, 16 waves/CU, 4 rows/wave).
// ---------------------------------------------------------------------------
__global__ __launch_bounds__(1024) void fused_mlp(
        const int* __restrict__ userIdx, const int* __restrict__ itemIdx,
        const float* __restrict__ uEmb, const float* __restrict__ iEmb,
        const unsigned short* __restrict__ feat1h,
        const unsigned short* __restrict__ feat2h,
        const float* __restrict__ W1, const float* __restrict__ b1,
        const float* __restrict__ W2, const float* __restrict__ b2,
        const float* __restrict__ W3, const float* __restrict__ b3,
        float* __restrict__ out) {
    __shared__ float    Wl[128 * 64];   // 32 KB  W1 chunk
    __shared__ unsigned El[64 * 64];    // 16 KB  E tile (bf16x2)
    __shared__ float    Ht[64 * 64];    // 16 KB  relu(E@W1+b1) tile
    __shared__ float    W2l[64 * 32];   // 8 KB
    __shared__ float    w3l[32];
    __shared__ float    b2l[32];
    __shared__ int      uidx[64], iidx[64];
    int tid = threadIdx.x;
    int lane = tid & 63;
    int wave = tid >> 6;                // 0..15
    int r0 = blockIdx.x * 64;
    int rbase = wave * 4;               // 4 rows per wave

    if (tid < 64) uidx[tid] = userIdx[r0 + tid];
    else if (tid < 128) iidx[tid - 64] = itemIdx[r0 + tid - 64];
    if (tid < 32) { w3l[tid] = W3[tid]; b2l[tid] = b2[tid]; }
    for (int i = tid; i < 64 * 32; i += 1024) W2l[i] = W2[i];

    float acc[4];
    float bv = b1[lane];
#pragma unroll
    for (int i = 0; i < 4; ++i) acc[i] = bv;

#pragma unroll 1
    for (int c = 0; c < 3; ++c) {
        __syncthreads();   // idx ready (c=0); El/Wl reuse safe (c>0)
        for (int i = tid; i < 128 * 64; i += 1024) Wl[i] = W1[c * 128 * 64 + i];
        {   // E-tile build: 1024 work items == 1024 threads (one gather each)
            int t = tid;                          // 64 rows x 2 segs x 8 quads
            int row = t >> 4;
            int seg = (t >> 3) & 1;
            int q   = t & 7;
            int gseg = c * 2 + seg;               // 0..5
            uint4 val;
            if (gseg == 0 || gseg == 3) {         // fp32 embedding segment
                const float* p = (gseg == 0)
                    ? uEmb + (size_t)uidx[row] * 64 + q * 8
                    : iEmb + (size_t)iidx[row] * 64 + q * 8;
                float4 a = *(const float4*)p;
                float4 b = *(const float4*)(p + 4);
                val.x = ((unsigned)f2bf(a.y) << 16) | f2bf(a.x);
                val.y = ((unsigned)f2bf(a.w) << 16) | f2bf(a.z);
                val.z = ((unsigned)f2bf(b.y) << 16) | f2bf(b.x);
                val.w = ((unsigned)f2bf(b.w) << 16) | f2bf(b.z);
            } else {
                const unsigned short* src;
                if (gseg == 1)      src = feat1h + (size_t)uidx[row] * 64;
                else if (gseg == 2) src = feat2h + (size_t)uidx[row] * 64;
                else if (gseg == 4) src = feat1h + (size_t)(iidx[row] + NUM_USERS) * 64;
                else                src = feat2h + (size_t)(iidx[row] + NUM_USERS) * 64;
                val = *(const uint4*)(src + q * 8);
            }
            *(uint4*)&El[row * 64 + seg * 32 + q * 4] = val;
        }
        __syncthreads();
        const uint4* El4 = (const uint4*)El;
#pragma unroll 1
        for (int k = 0; k < 128; k += 8) {
            float w0 = Wl[(k + 0) * 64 + lane];
            float w1 = Wl[(k + 1) * 64 + lane];
            float w2 = Wl[(k + 2) * 64 + lane];
            float w3 = Wl[(k + 3) * 64 + lane];
            float w4 = Wl[(k + 4) * 64 + lane];
            float w5 = Wl[(k + 5) * 64 + lane];
            float w6 = Wl[(k + 6) * 64 + lane];
            float w7 = Wl[(k + 7) * 64 + lane];
#pragma unroll
            for (int i = 0; i < 4; ++i) {
                uint4 q = El4[(rbase + i) * 16 + (k >> 3)];   // LDS broadcast
                acc[i] = fmaf(bflo(q.x), w0, acc[i]);
                acc[i] = fmaf(bfhi(q.x), w1, acc[i]);
                acc[i] = fmaf(bflo(q.y), w2, acc[i]);
                acc[i] = fmaf(bfhi(q.y), w3, acc[i]);
                acc[i] = fmaf(bflo(q.z), w4, acc[i]);
                acc[i] = fmaf(bfhi(q.z), w5, acc[i]);
                acc[i] = fmaf(bflo(q.w), w6, acc[i]);
                acc[i] = fmaf(bfhi(q.w), w7, acc[i]);
            }
        }
    }

    // H-tile: relu
#pragma unroll
    for (int i = 0; i < 4; ++i) Ht[(rbase + i) * 64 + lane] = fmaxf(acc[i], 0.f);
    __syncthreads();

    // W2/W3 finish: half-wave per row (lanes k<32 = W2 cols), shfl reduce
    int half = lane >> 5;
    int k = lane & 31;
    float b3v = b3[0];
#pragma unroll 1
    for (int p = 0; p < 2; ++p) {
        int row = rbase + p * 2 + half;
        float z = b2l[k];
#pragma unroll
        for (int j = 0; j < 64; ++j)
            z = fmaf(Ht[row * 64 + j], W2l[j * 32 + k], z);
        z *= w3l[k];
#pragma unroll
        for (int off = 16; off; off >>= 1)
            z += __shfl_xor(z, off, 64);
        if (k == 0) out[r0 + row] = z + b3v;
    }
}

// ---------------------------------------------------------------------------
extern "C" void kernel_launch(void* const* d_in, const int* in_sizes, int n_in,
                              void* d_out, int out_size, void* d_ws, size_t ws_size,
                              hipStream_t stream) {
    const int*   userIdx = (const int*)  d_in[0];
    const int*   itemIdx = (const int*)  d_in[1];
    const int*   lap_rows= (const int*)  d_in[2];
    const int*   lap_cols= (const int*)  d_in[3];
    const float* lap_vals= (const float*)d_in[4];
    const float* uEmb    = (const float*)d_in[5];
    const float* iEmb    = (const float*)d_in[6];
    const float* gW0     = (const float*)d_in[7];
    const float* gb0     = (const float*)d_in[8];
    const float* gW1     = (const float*)d_in[9];
    const float* gb1     = (const float*)d_in[10];
    const float* W1      = (const float*)d_in[11];
    const float* b1      = (const float*)d_in[12];
    const float* W2      = (const float*)d_in[13];
    const float* b2      = (const float*)d_in[14];
    const float* W3      = (const float*)d_in[15];
    const float* b3      = (const float*)d_in[16];
    float* out = (float*)d_out;

    const size_t NF = (size_t)N_NODES * EMB;              // 9.6M elements
    char* w = (char*)d_ws;
    unsigned short* bufA = (unsigned short*)w;            // feat1h (19.2 MB)
    unsigned short* bufB = bufA + NF;                     // feat2h (19.2 MB)
    char*  region3 = (char*)(bufB + NF);                  // 38.4 MB multi-use
    // region3 first half: pv during CSR build, then Zh
    int2*  pv      = (int2*)region3;                      // 19.2 MB (dead after fine_scatter)
    unsigned short* Zh = (unsigned short*)region3;        // Z table (19.2 MB)
    // region3 second half: packed lives through both spmm calls
    int2*  packed  = (int2*)(region3 + NF * sizeof(float)); // 19.2 MB
    int*   row_ptr = (int*)(packed + NNZ);                // N_NODES+1
    int*   boffs   = row_ptr + (N_NODES + 1);             // NBUCK+1 (immutable)
    int*   gtails  = boffs + (NBUCK + 1);                 // NBUCK (mutable tails)
    int*   bcnt    = gtails + NBUCK;                      // NBUCK

    const int ms_grid   = (NNZ + EPB - 1) / EPB;          // 256 (1 block/CU)
    const int ms_lds    = EPB * 12;                       // stage (8B) + smap (4B)
    const int spmm_grid = (N_NODES + 3) / 4;              // 37500
    const int gemm_grid = (N_NODES + 63) / 64;            // 2344

    // ---- Build bucketed CSR (shared by both layers) — round-2 pipeline
    hipMemsetAsync(bcnt, 0, NBUCK * sizeof(int), stream);
    bucket_hist<<<256, 1024, 0, stream>>>(lap_rows, bcnt, NNZ);
    bucket_scan<<<1, 1024, 0, stream>>>(bcnt, boffs, gtails, NNZ);
    coarse_multisplit<<<ms_grid, 1024, ms_lds, stream>>>(lap_rows, lap_cols, lap_vals,
                                                         gtails, pv, NNZ);
    fine_scatter<<<NBUCK, 1024, 0, stream>>>(boffs, pv, packed, row_ptr, NNZ);

    // ---- Layer 1: Z = concat(uEmb,iEmb)@gW0 ; feat1 = relu((L+I)Z + gb0)
    gemm_table_f32<<<gemm_grid, 256, 0, stream>>>(uEmb, iEmb, gW0, Zh, N_NODES);
    spmm_bias_relu<<<spmm_grid, 256, 0, stream>>>(row_ptr, packed, (const uint2*)Zh,
                                                  gb0, (uint2*)bufA, N_NODES);

    // ---- Layer 2: Z = feat1@gW1 ; feat2 = relu((L+I)Z + gb1)
    gemm_table_bf16<<<gemm_grid, 256, 0, stream>>>((const unsigned*)bufA, gW1, Zh, N_NODES);
    spmm_bias_relu<<<spmm_grid, 256, 0, stream>>>(row_ptr, packed, (const uint2*)Zh,
                                                  gb1, (uint2*)bufB, N_NODES);

    // ---- Fused MLP: gather + E@W1+b1+relu + @W2+b2 + @W3+b3
    fused_mlp<<<BATCH / 64, 1024, 0, stream>>>(userIdx, itemIdx, uEmb, iEmb,
                                               bufA, bufB, W1, b1, W2, b2, W3, b3, out);
}

// Round 10
// 420.685 us; speedup vs baseline: 1.1952x; 1.0919x over previous
//
#include <hip/hip_runtime.h>
#include <hip/hip_bf16.h>

// Problem constants (from reference)
#define NUM_USERS 100000
#define NUM_ITEMS 50000
#define N_NODES   150000   // NUM_USERS + NUM_ITEMS
#define EMB       64
#define NNZ       2400000
#define BATCH     16384
#define D_CAT     384      // EMB*3*2
#define BSHIFT    8        // 256 rows per bucket: multisplit segment ~2 lines
#define NBUCK     ((N_NODES + 255) >> 8)   // 586
#define EPB       9375     // edges per multisplit block -> grid = exactly 256

typedef __attribute__((ext_vector_type(8))) short bf16x8;   // MFMA A/B frag (4 VGPR)
typedef __attribute__((ext_vector_type(4))) float f32x4;    // MFMA C/D frag

// ---- bf16 helpers (bit-level, RN-even for f32->bf16) -----------------------
__device__ __forceinline__ unsigned short f2bf(float f) {
    unsigned u = __float_as_uint(f);
    unsigned r = u + 0x7fffu + ((u >> 16) & 1u);
    return (unsigned short)(r >> 16);
}
__device__ __forceinline__ float bflo(unsigned u) { return __uint_as_float(u << 16); }
__device__ __forceinline__ float bfhi(unsigned u) { return __uint_as_float(u & 0xffff0000u); }
__device__ __forceinline__ float bf2f(unsigned short h) {
    return __uint_as_float((unsigned)h << 16);
}

// ---------------------------------------------------------------------------
// Bucket histogram, LDS-aggregated (round-2 proven: 256 blocks).
// ---------------------------------------------------------------------------
__global__ __launch_bounds__(1024) void bucket_hist(const int* __restrict__ rows,
                                                    int* __restrict__ bcnt, int nnz) {
    __shared__ int h[NBUCK];
    int tid = threadIdx.x;
    for (int i = tid; i < NBUCK; i += 1024) h[i] = 0;
    __syncthreads();
    for (int i = blockIdx.x * 1024 + tid; i < nnz; i += gridDim.x * 1024)
        atomicAdd(&h[rows[i] >> BSHIFT], 1);
    __syncthreads();
    for (int i = tid; i < NBUCK; i += 1024) {
        int c = h[i];
        if (c) atomicAdd(&bcnt[i], c);
    }
}

// ---------------------------------------------------------------------------
// Exclusive scan over the 586 bucket counts (single block, 1 elem/thread).
// ---------------------------------------------------------------------------
__global__ __launch_bounds__(1024) void bucket_scan(const int* __restrict__ bcnt,
                                                    int* __restrict__ boffs,
                                                    int* __restrict__ gtails, int nnz) {
    __shared__ int s[1024];
    int t = threadIdx.x;
    int x = (t < NBUCK) ? bcnt[t] : 0;
    s[t] = x;
    __syncthreads();
#pragma unroll
    for (int off = 1; off < 1024; off <<= 1) {
        int v = (t >= off) ? s[t - off] : 0;
        __syncthreads();
        s[t] += v;
        __syncthreads();
    }
    if (t < NBUCK) {
        int e = s[t] - x;
        boffs[t] = e;
        gtails[t] = e;
    }
    if (t == 0) boffs[NBUCK] = nnz;
}

// ---------------------------------------------------------------------------
// LDS-staged multisplit into 256-row buckets (round-15 proven).
// pv payload: .x = (r_local<<18) | col  (rl<256, col<2^18), .y = val
// ---------------------------------------------------------------------------
__global__ __launch_bounds__(1024) void coarse_multisplit(const int* __restrict__ rows,
                                                          const int* __restrict__ cols,
                                                          const float* __restrict__ vals,
                                                          int* __restrict__ gtails,
                                                          int2* __restrict__ pv, int nnz) {
    extern __shared__ int dyn[];
    int2* stage = (int2*)dyn;          // [EPB]  bucket-sorted payloads (75 KB)
    int*  smap  = dyn + 2 * EPB;       // [EPB]  per-slot dst shift (37.5 KB)
    __shared__ int hcnt[NBUCK];        // counts -> then local bump cursors
    __shared__ int lstart[NBUCK];      // local exclusive prefix (immutable)
    __shared__ int shiftv[NBUCK];      // global base - local start

    int tid = threadIdx.x;
    int e0 = blockIdx.x * EPB;
    int e1 = e0 + EPB < nnz ? e0 + EPB : nnz;
    int nE = e1 - e0;

    // phase 1: local histogram
    for (int i = tid; i < NBUCK; i += 1024) hcnt[i] = 0;
    __syncthreads();
    for (int i = e0 + tid; i < e1; i += 1024)
        atomicAdd(&hcnt[rows[i] >> BSHIFT], 1);
    __syncthreads();

    // phase 2: local scan (Hillis-Steele over 1024 slots; smap[0:1024) scratch)
    int cnt = (tid < NBUCK) ? hcnt[tid] : 0;
    smap[tid] = cnt;
    __syncthreads();
#pragma unroll
    for (int off = 1; off < 1024; off <<= 1) {
        int v = (tid >= off) ? smap[tid - off] : 0;
        __syncthreads();
        smap[tid] += v;
        __syncthreads();
    }
    if (tid < NBUCK) {
        int ls = smap[tid] - cnt;      // exclusive local prefix
        lstart[tid] = ls;
        hcnt[tid] = ls;                // init bump cursor
        int gb = cnt ? atomicAdd(&gtails[tid], cnt) : 0;  // global base
        shiftv[tid] = gb - ls;
    }
    __syncthreads();

    // phase 3: fill per-slot shift map (avg 14, bounded run per bucket)
    for (int b = tid; b < NBUCK; b += 1024) {
        int beg = lstart[b];
        int end_ = (b == NBUCK - 1) ? nE : lstart[b + 1];
        int sh = shiftv[b];
        for (int k = beg; k < end_; ++k) smap[k] = sh;
    }
    __syncthreads();

    // phase 4: placement into bucket-sorted LDS slots (rows re-read: L2-warm)
    for (int i = e0 + tid; i < e1; i += 1024) {
        int r = rows[i];
        int p = atomicAdd(&hcnt[r >> BSHIFT], 1);
        stage[p] = make_int2(((r & 255) << 18) | cols[i], __float_as_int(vals[i]));
    }
    __syncthreads();

    // phase 5: coalesced flush (consecutive lanes -> consecutive dst per run)
    for (int j = tid; j < nE; j += 1024)
        pv[smap[j] + j] = stage[j];
}

// ---------------------------------------------------------------------------
// Fine scatter within a 256-row bucket + row_ptr production.
// ---------------------------------------------------------------------------
__global__ __launch_bounds__(1024) void fine_scatter(const int* __restrict__ boffs,
                                                     const int2* __restrict__ pv,
                                                     int2* __restrict__ packed,
                                                     int* __restrict__ row_ptr, int nnz) {
    __shared__ int rcnt[256];
    __shared__ int loff[256];
    int b = blockIdx.x;
    int tid = threadIdx.x;
    int lo = boffs[b], hi = boffs[b + 1];
    int r0 = b << BSHIFT;
    int nr = N_NODES - r0; if (nr > 256) nr = 256;

    if (tid < 256) rcnt[tid] = 0;
    __syncthreads();
    for (int i = lo + tid; i < hi; i += 1024)
        atomicAdd(&rcnt[pv[i].x >> 18], 1);
    __syncthreads();
    if (tid < 256) loff[tid] = rcnt[tid];
    __syncthreads();
#pragma unroll
    for (int off = 1; off < 256; off <<= 1) {
        int v = (tid < 256 && tid >= off) ? loff[tid - off] : 0;
        __syncthreads();
        if (tid < 256) loff[tid] += v;
        __syncthreads();
    }
    if (tid < 256) {
        int e = lo + loff[tid] - rcnt[tid];    // exclusive prefix + bucket base
        loff[tid] = e;
        if (tid < nr) row_ptr[r0 + tid] = e;
    }
    if (b == 0 && tid == 0) row_ptr[N_NODES] = nnz;
    __syncthreads();
    for (int i = lo + tid; i < hi; i += 1024) {
        int2 e = pv[i];
        int rl = e.x >> 18;
        int pos = atomicAdd(&loff[rl], 1);
        packed[pos] = make_int2(e.x & 0x3FFFF, e.y);
    }
}

// ---------------------------------------------------------------------------
// Table GEMM via MFMA (round-24). Rounds 4/7/8/9 proved every SOFTWARE
// broadcast of the X row (LDS same-addr read, shfl, readlane) costs the same
// ~96 us combined — the matrix core does this broadcast in hardware.
// Z = X @ W, X [n_rows x 64], W [64 x 64] f32, output bf16.
// No fp32-input MFMA on CDNA4 -> 2-term bf16 split: W = Wh + Wl;
//   L1 (f32 X):  Z = Xh@Wh + Xl@Wh + Xh@Wl   (3 products, err ~2^-16)
//   L2 (bf16 X): Z = X@Wh + X@Wl             (2 products, X exact)
// Residuals are far below the output's own bf16 rounding -> absmax ~1e-3.
// Fragment layout (16x16x32): A row=lane&15, k=8*(lane>>4)+e; B col=lane&15,
// same k; C/D col=lane&15, row=(lane>>4)*4+reg (m89-verified).
// Per block: 256 rows (4 waves x 4 row-tiles); W frags built once from LDS.
// ---------------------------------------------------------------------------
template<int L1>
__global__ __launch_bounds__(256) void gemm_table_mfma(
        const float* __restrict__ uE, const float* __restrict__ iE,
        const unsigned short* __restrict__ Xh,
        const float* __restrict__ W,
        unsigned short* __restrict__ Zh, int n_rows) {
    __shared__ float Wlds[64 * 64];    // 16 KB, staged once (coalesced)
    int tid = threadIdx.x;
    int lane = tid & 63;
    int wave = tid >> 6;
    int l16 = lane & 15;               // frag row (A) / col (B,D)
    int lg  = lane >> 4;               // k-group (A,B) / row-group (D)
    int last = n_rows - 1;

    for (int i = tid; i < 64 * 64; i += 256) Wlds[i] = W[i];
    __syncthreads();

    // B-frags: elem e of (ks,ct) = W[32*ks + 8*lg + e][l16 + 16*ct], split.
    bf16x8 Bh[2][4], Bl[2][4];
#pragma unroll
    for (int ks = 0; ks < 2; ++ks)
#pragma unroll
        for (int ct = 0; ct < 4; ++ct) {
            bf16x8 h, l;
#pragma unroll
            for (int e = 0; e < 8; ++e) {
                float w = Wlds[(32 * ks + 8 * lg + e) * 64 + l16 + 16 * ct];
                unsigned short hh = f2bf(w);
                h[e] = (short)hh;
                l[e] = (short)f2bf(w - bf2f(hh));
            }
            Bh[ks][ct] = h;
            Bl[ks][ct] = l;
        }

    int rbase = blockIdx.x * 256 + wave * 64;
#pragma unroll 1
    for (int rt = 0; rt < 4; ++rt) {
        int r0 = rbase + rt * 16;
        int rr = r0 + l16; rr = rr > last ? last : rr;   // clamped A-row

        f32x4 acc[4];
#pragma unroll
        for (int ct = 0; ct < 4; ++ct) acc[ct] = (f32x4){0.f, 0.f, 0.f, 0.f};

#pragma unroll
        for (int ks = 0; ks < 2; ++ks) {
            if constexpr (L1) {
                const float* xp = (rr < NUM_USERS)
                    ? uE + (size_t)rr * 64
                    : iE + (size_t)(rr - NUM_USERS) * 64;
                float4 a0 = *(const float4*)(xp + 32 * ks + 8 * lg);
                float4 a1 = *(const float4*)(xp + 32 * ks + 8 * lg + 4);
                float av[8] = {a0.x, a0.y, a0.z, a0.w, a1.x, a1.y, a1.z, a1.w};
                bf16x8 Ah, Al;
#pragma unroll
                for (int e = 0; e < 8; ++e) {
                    unsigned short hh = f2bf(av[e]);
                    Ah[e] = (short)hh;
                    Al[e] = (short)f2bf(av[e] - bf2f(hh));
                }
#pragma unroll
                for (int ct = 0; ct < 4; ++ct) {
                    acc[ct] = __builtin_amdgcn_mfma_f32_16x16x32_bf16(Ah, Bh[ks][ct], acc[ct], 0, 0, 0);
                    acc[ct] = __builtin_amdgcn_mfma_f32_16x16x32_bf16(Al, Bh[ks][ct], acc[ct], 0, 0, 0);
                    acc[ct] = __builtin_amdgcn_mfma_f32_16x16x32_bf16(Ah, Bl[ks][ct], acc[ct], 0, 0, 0);
                }
            } else {
                bf16x8 A = *(const bf16x8*)(Xh + (size_t)rr * 64 + 32 * ks + 8 * lg);
#pragma unroll
                for (int ct = 0; ct < 4; ++ct) {
                    acc[ct] = __builtin_amdgcn_mfma_f32_16x16x32_bf16(A, Bh[ks][ct], acc[ct], 0, 0, 0);
                    acc[ct] = __builtin_amdgcn_mfma_f32_16x16x32_bf16(A, Bl[ks][ct], acc[ct], 0, 0, 0);
                }
            }
        }

        // D: lane l16=col, rows r0 + lg*4 + i
#pragma unroll
        for (int ct = 0; ct < 4; ++ct)
#pragma unroll
            for (int i = 0; i < 4; ++i) {
                int r = r0 + lg * 4 + i;
                if (r < n_rows)
                    Zh[(size_t)r * 64 + l16 + 16 * ct] = f2bf(acc[ct][i]);
            }
    }
}

// ---------------------------------------------------------------------------
// SPMM + bias + relu (round-2 proven, 1 row/wave, 23 waves/CU) — BOTH layers.
// Latency-bound, occupancy-critical: 3 fusion attempts all regressed. Frozen.
// ---------------------------------------------------------------------------
__global__ __launch_bounds__(256) void spmm_bias_relu(const int* __restrict__ row_ptr,
                                                      const int2* __restrict__ packed,
                                                      const uint2* __restrict__ zh2,   // bf16x4, 16/row
                                                      const float* __restrict__ bias,  // [64] fp32
                                                      uint2* __restrict__ outh2,       // bf16x4, 16/row
                                                      int n_rows) {
    int tid = threadIdx.x;
    int lane = tid & 63;
    int wave = tid >> 6;
    int q = lane >> 4;                 // 0..3 quarter
    int k = lane & 15;                 // column group (4 cols per lane)
    int r = blockIdx.x * 4 + wave;
    if (r >= n_rows) return;

    uint2 su = zh2[(size_t)r * 16 + k];
    float4 acc;
    acc.x = q ? 0.f : bflo(su.x);
    acc.y = q ? 0.f : bfhi(su.x);
    acc.z = q ? 0.f : bflo(su.y);
    acc.w = q ? 0.f : bfhi(su.y);

    int e = row_ptr[r] + q;
    int end = row_ptr[r + 1];
    for (; e + 13 < end; e += 16) {    // 16 edges/iter (4 per quarter)
        int2 p0 = packed[e + 0];
        int2 p1 = packed[e + 4];
        int2 p2 = packed[e + 8];
        int2 p3 = packed[e + 12];
        uint2 z0 = zh2[(size_t)p0.x * 16 + k];
        uint2 z1 = zh2[(size_t)p1.x * 16 + k];
        uint2 z2 = zh2[(size_t)p2.x * 16 + k];
        uint2 z3 = zh2[(size_t)p3.x * 16 + k];
        float v0 = __int_as_float(p0.y), v1 = __int_as_float(p1.y);
        float v2 = __int_as_float(p2.y), v3 = __int_as_float(p3.y);
        acc.x = fmaf(v0, bflo(z0.x), acc.x); acc.y = fmaf(v0, bfhi(z0.x), acc.y);
        acc.z = fmaf(v0, bflo(z0.y), acc.z); acc.w = fmaf(v0, bfhi(z0.y), acc.w);
        acc.x = fmaf(v1, bflo(z1.x), acc.x); acc.y = fmaf(v1, bfhi(z1.x), acc.y);
        acc.z = fmaf(v1, bflo(z1.y), acc.z); acc.w = fmaf(v1, bfhi(z1.y), acc.w);
        acc.x = fmaf(v2, bflo(z2.x), acc.x); acc.y = fmaf(v2, bfhi(z2.x), acc.y);
        acc.z = fmaf(v2, bflo(z2.y), acc.z); acc.w = fmaf(v2, bfhi(z2.y), acc.w);
        acc.x = fmaf(v3, bflo(z3.x), acc.x); acc.y = fmaf(v3, bfhi(z3.x), acc.y);
        acc.z = fmaf(v3, bflo(z3.y), acc.z); acc.w = fmaf(v3, bfhi(z3.y), acc.w);
    }
    for (; e < end; e += 4) {
        int2 p = packed[e];
        uint2 z = zh2[(size_t)p.x * 16 + k];
        float v = __int_as_float(p.y);
        acc.x = fmaf(v, bflo(z.x), acc.x); acc.y = fmaf(v, bfhi(z.x), acc.y);
        acc.z = fmaf(v, bflo(z.y), acc.z); acc.w = fmaf(v, bfhi(z.y), acc.w);
    }

    acc.x += __shfl_xor(acc.x, 16, 64);
    acc.y += __shfl_xor(acc.y, 16, 64);
    acc.z += __shfl_xor(acc.z, 16, 64);
    acc.w += __shfl_xor(acc.w, 16, 64);
    acc.x += __shfl_xor(acc.x, 32, 64);
    acc.y += __shfl_xor(acc.y, 32, 64);
    acc.z += __shfl_xor(acc.z, 32, 64);
    acc.w += __shfl_xor(acc.w, 32, 64);
    if (q == 0) {
        float4 bv = ((const float4*)bias)[k];
        float a = fmaxf(acc.x + bv.x, 0.f);
        float b = fmaxf(acc.y + bv.y, 0.f);
        float c = fmaxf(acc.z + bv.z, 0.f);
        float d = fmaxf(acc.w + bv.w, 0.f);
        outh2[(size_t)r * 16 + k] = make_uint2(
            ((unsigned)f2bf(b) << 16) | (unsigned)f2bf(a),
            ((unsigned)f2bf(d) << 16) | (unsigned)f2bf(c));
    }
}

// ---------------------------------------------------------------------------
// Fused MLP (round-16 proven: 1024 threads/block, 16 waves/CU, 4 rows/wave).
// ---------------------------------------------------------------------------
__global__ __launch_bounds__(1024) void fused_mlp(
        const int* __restrict__ userIdx, const int* __restrict__ itemIdx,
        const float* __restrict__ uEmb, const float* __restrict__ iEmb,
        const unsigned short* __restrict__ feat1h,
        const unsigned short* __restrict__ feat2h,
        const float* __restrict__ W1, const float* __restrict__ b1,
        const float* __restrict__ W2, const float* __restrict__ b2,
        const float* __restrict__ W3, const float* __restrict__ b3,
        float* __restrict__ out) {
    __shared__ float    Wl[128 * 64];   // 32 KB  W1 chunk
    __shared__ unsigned El[64 * 64];    // 16 KB  E tile (bf16x2)
    __shared__ float    Ht[64 * 64];    // 16 KB  relu(E@W1+b1) tile
    __shared__ float    W2l[64 * 32];   // 8 KB
    __shared__ float    w3l[32];
    __shared__ float    b2l[32];
    __shared__ int      uidx[64], iidx[64];
    int tid = threadIdx.x;
    int lane = tid & 63;
    int wave = tid >> 6;                // 0..15
    int r0 = blockIdx.x * 64;
    int rbase = wave * 4;               // 4 rows per wave

    if (tid < 64) uidx[tid] = userIdx[r0 + tid];
    else if (tid < 128) iidx[tid - 64] = itemIdx[r0 + tid - 64];
    if (tid < 32) { w3l[tid] = W3[tid]; b2l[tid] = b2[tid]; }
    for (int i = tid; i < 64 * 32; i += 1024) W2l[i] = W2[i];

    float acc[4];
    float bv = b1[lane];
#pragma unroll
    for (int i = 0; i < 4; ++i) acc[i] = bv;

#pragma unroll 1
    for (int c = 0; c < 3; ++c) {
        __syncthreads();   // idx ready (c=0); El/Wl reuse safe (c>0)
        for (int i = tid; i < 128 * 64; i += 1024) Wl[i] = W1[c * 128 * 64 + i];
        {   // E-tile build: 1024 work items == 1024 threads (one gather each)
            int t = tid;                          // 64 rows x 2 segs x 8 quads
            int row = t >> 4;
            int seg = (t >> 3) & 1;
            int q   = t & 7;
            int gseg = c * 2 + seg;               // 0..5
            uint4 val;
            if (gseg == 0 || gseg == 3) {         // fp32 embedding segment
                const float* p = (gseg == 0)
                    ? uEmb + (size_t)uidx[row] * 64 + q * 8
                    : iEmb + (size_t)iidx[row] * 64 + q * 8;
                float4 a = *(const float4*)p;
                float4 b = *(const float4*)(p + 4);
                val.x = ((unsigned)f2bf(a.y) << 16) | f2bf(a.x);
                val.y = ((unsigned)f2bf(a.w) << 16) | f2bf(a.z);
                val.z = ((unsigned)f2bf(b.y) << 16) | f2bf(b.x);
                val.w = ((unsigned)f2bf(b.w) << 16) | f2bf(b.z);
            } else {
                const unsigned short* src;
                if (gseg == 1)      src = feat1h + (size_t)uidx[row] * 64;
                else if (gseg == 2) src = feat2h + (size_t)uidx[row] * 64;
                else if (gseg == 4) src = feat1h + (size_t)(iidx[row] + NUM_USERS) * 64;
                else                src = feat2h + (size_t)(iidx[row] + NUM_USERS) * 64;
                val = *(const uint4*)(src + q * 8);
            }
            *(uint4*)&El[row * 64 + seg * 32 + q * 4] = val;
        }
        __syncthreads();
        const uint4* El4 = (const uint4*)El;
#pragma unroll 1
        for (int k = 0; k < 128; k += 8) {
            float w0 = Wl[(k + 0) * 64 + lane];
            float w1 = Wl[(k + 1) * 64 + lane];
            float w2 = Wl[(k + 2) * 64 + lane];
            float w3 = Wl[(k + 3) * 64 + lane];
            float w4 = Wl[(k + 4) * 64 + lane];
            float w5 = Wl[(k + 5) * 64 + lane];
            float w6 = Wl[(k + 6) * 64 + lane];
            float w7 = Wl[(k + 7) * 64 + lane];
#pragma unroll
            for (int i = 0; i < 4; ++i) {
                uint4 q = El4[(rbase + i) * 16 + (k >> 3)];   // LDS broadcast
                acc[i] = fmaf(bflo(q.x), w0, acc[i]);
                acc[i] = fmaf(bfhi(q.x), w1, acc[i]);
                acc[i] = fmaf(bflo(q.y), w2, acc[i]);
                acc[i] = fmaf(bfhi(q.y), w3, acc[i]);
                acc[i] = fmaf(bflo(q.z), w4, acc[i]);
                acc[i] = fmaf(bfhi(q.z), w5, acc[i]);
                acc[i] = fmaf(bflo(q.w), w6, acc[i]);
                acc[i] = fmaf(bfhi(q.w), w7, acc[i]);
            }
        }
    }

    // H-tile: relu
#pragma unroll
    for (int i = 0; i < 4; ++i) Ht[(rbase + i) * 64 + lane] = fmaxf(acc[i], 0.f);
    __syncthreads();

    // W2/W3 finish: half-wave per row (lanes k<32 = W2 cols), shfl reduce
    int half = lane >> 5;
    int k = lane & 31;
    float b3v = b3[0];
#pragma unroll 1
    for (int p = 0; p < 2; ++p) {
        int row = rbase + p * 2 + half;
        float z = b2l[k];
#pragma unroll
        for (int j = 0; j < 64; ++j)
            z = fmaf(Ht[row * 64 + j], W2l[j * 32 + k], z);
        z *= w3l[k];
#pragma unroll
        for (int off = 16; off; off >>= 1)
            z += __shfl_xor(z, off, 64);
        if (k == 0) out[r0 + row] = z + b3v;
    }
}

// ---------------------------------------------------------------------------
extern "C" void kernel_launch(void* const* d_in, const int* in_sizes, int n_in,
                              void* d_out, int out_size, void* d_ws, size_t ws_size,
                              hipStream_t stream) {
    const int*   userIdx = (const int*)  d_in[0];
    const int*   itemIdx = (const int*)  d_in[1];
    const int*   lap_rows= (const int*)  d_in[2];
    const int*   lap_cols= (const int*)  d_in[3];
    const float* lap_vals= (const float*)d_in[4];
    const float* uEmb    = (const float*)d_in[5];
    const float* iEmb    = (const float*)d_in[6];
    const float* gW0     = (const float*)d_in[7];
    const float* gb0     = (const float*)d_in[8];
    const float* gW1     = (const float*)d_in[9];
    const float* gb1     = (const float*)d_in[10];
    const float* W1      = (const float*)d_in[11];
    const float* b1      = (const float*)d_in[12];
    const float* W2      = (const float*)d_in[13];
    const float* b2      = (const float*)d_in[14];
    const float* W3      = (const float*)d_in[15];
    const float* b3      = (const float*)d_in[16];
    float* out = (float*)d_out;

    const size_t NF = (size_t)N_NODES * EMB;              // 9.6M elements
    char* w = (char*)d_ws;
    unsigned short* bufA = (unsigned short*)w;            // feat1h (19.2 MB)
    unsigned short* bufB = bufA + NF;                     // feat2h (19.2 MB)
    char*  region3 = (char*)(bufB + NF);                  // 38.4 MB multi-use
    // region3 first half: pv during CSR build, then Zh
    int2*  pv      = (int2*)region3;                      // 19.2 MB (dead after fine_scatter)
    unsigned short* Zh = (unsigned short*)region3;        // Z table (19.2 MB)
    // region3 second half: packed lives through both spmm calls
    int2*  packed  = (int2*)(region3 + NF * sizeof(float)); // 19.2 MB
    int*   row_ptr = (int*)(packed + NNZ);                // N_NODES+1
    int*   boffs   = row_ptr + (N_NODES + 1);             // NBUCK+1 (immutable)
    int*   gtails  = boffs + (NBUCK + 1);                 // NBUCK (mutable tails)
    int*   bcnt    = gtails + NBUCK;                      // NBUCK

    const int ms_grid   = (NNZ + EPB - 1) / EPB;          // 256 (1 block/CU)
    const int ms_lds    = EPB * 12;                       // stage (8B) + smap (4B)
    const int spmm_grid = (N_NODES + 3) / 4;              // 37500
    const int mfma_grid = (N_NODES + 255) / 256;          // 586 (256 rows/block)

    // ---- Build bucketed CSR (shared by both layers) — round-2 pipeline
    hipMemsetAsync(bcnt, 0, NBUCK * sizeof(int), stream);
    bucket_hist<<<256, 1024, 0, stream>>>(lap_rows, bcnt, NNZ);
    bucket_scan<<<1, 1024, 0, stream>>>(bcnt, boffs, gtails, NNZ);
    coarse_multisplit<<<ms_grid, 1024, ms_lds, stream>>>(lap_rows, lap_cols, lap_vals,
                                                         gtails, pv, NNZ);
    fine_scatter<<<NBUCK, 1024, 0, stream>>>(boffs, pv, packed, row_ptr, NNZ);

    // ---- Layer 1: Z = concat(uEmb,iEmb)@gW0 ; feat1 = relu((L+I)Z + gb0)
    gemm_table_mfma<1><<<mfma_grid, 256, 0, stream>>>(uEmb, iEmb, nullptr,
                                                      gW0, Zh, N_NODES);
    spmm_bias_relu<<<spmm_grid, 256, 0, stream>>>(row_ptr, packed, (const uint2*)Zh,
                                                  gb0, (uint2*)bufA, N_NODES);

    // ---- Layer 2: Z = feat1@gW1 ; feat2 = relu((L+I)Z + gb1)
    gemm_table_mfma<0><<<mfma_grid, 256, 0, stream>>>(nullptr, nullptr, bufA,
                                                      gW1, Zh, N_NODES);
    spmm_bias_relu<<<spmm_grid, 256, 0, stream>>>(row_ptr, packed, (const uint2*)Zh,
                                                  gb1, (uint2*)bufB, N_NODES);

    // ---- Fused MLP: gather + E@W1+b1+relu + @W2+b2 + @W3+b3
    fused_mlp<<<BATCH / 64, 1024, 0, stream>>>(userIdx, itemIdx, uEmb, iEmb,
                                               bufA, bufB, W1, b1, W2, b2, W3, b3, out);
}